// Round 1
// baseline (1025.733 us; speedup 1.0000x reference)
//
#include <hip/hip_runtime.h>
#include <cstdint>

#define N_NODES 50000
#define IN_DIM  256
#define HID     128
#define OUT_DIM 64
#define N_EDGES 800000
#define BATCH   4096
#define BN_EPS  1e-5f
#define SLOPE   0.01f

// ---------------- CSR build ----------------

__global__ void count_deg(const int* __restrict__ dst, int* __restrict__ cnt) {
    int e = blockIdx.x * blockDim.x + threadIdx.x;
    if (e < N_EDGES) atomicAdd(&cnt[dst[e]], 1);
}

__global__ void compute_dinv(const int* __restrict__ cnt, float* __restrict__ dinv) {
    int n = blockIdx.x * blockDim.x + threadIdx.x;
    if (n < N_NODES) dinv[n] = rsqrtf(1.0f + (float)cnt[n]);
}

// single-block exclusive scan over cnt -> rowstart[0..N_NODES]
__global__ void scan_kernel(const int* __restrict__ cnt, int* __restrict__ rowstart) {
    __shared__ int sdata[1024];
    const int CHUNK = (N_NODES + 1023) / 1024;   // 49
    int t = threadIdx.x;
    int lo = t * CHUNK;
    int hi = min(lo + CHUNK, N_NODES);
    int loc = 0;
    for (int i = lo; i < hi; ++i) loc += cnt[i];
    sdata[t] = loc;
    __syncthreads();
    for (int off = 1; off < 1024; off <<= 1) {
        int v = (t >= off) ? sdata[t - off] : 0;
        __syncthreads();
        sdata[t] += v;
        __syncthreads();
    }
    int run = sdata[t] - loc;   // exclusive prefix of this thread's chunk
    for (int i = lo; i < hi; ++i) { rowstart[i] = run; run += cnt[i]; }
    if (t == 1023) rowstart[N_NODES] = sdata[1023];
}

__global__ void scatter_edges(const int* __restrict__ src, const int* __restrict__ dst,
                              const int* __restrict__ rowstart, int* __restrict__ cursor,
                              int* __restrict__ csr) {
    int e = blockIdx.x * blockDim.x + threadIdx.x;
    if (e < N_EDGES) {
        int d = dst[e];
        int pos = rowstart[d] + atomicAdd(&cursor[d], 1);
        csr[pos] = src[e];
    }
}

// ---------------- small transpose: W[R][C] -> Wt[C][R] ----------------

__global__ void transpose_k(const float* __restrict__ W, float* __restrict__ Wt, int R, int C) {
    int idx = blockIdx.x * blockDim.x + threadIdx.x;
    if (idx < R * C) {
        int c = idx / R, r = idx % R;
        Wt[idx] = W[r * C + c];
    }
}

// ---------------- fp32 tiled GEMM: C[M][BN] = A[M][K] @ B[K][BN] (+bias) ----------------
// BM=64, BK=32, 256 threads, per-thread 4 x TN microtile. N == BN (full width).

template<int BN, int TN>
__global__ __launch_bounds__(256) void gemm_kernel(const float* __restrict__ A,
                                                   const float* __restrict__ B,
                                                   const float* __restrict__ bias,
                                                   float* __restrict__ C,
                                                   int M, int K) {
    constexpr int BM = 64, BK = 32, TM = 4;
    __shared__ float As[BK][BM];
    __shared__ float Bs[BK][BN];
    const int tid = threadIdx.x;
    const int tx = tid & 15, ty = tid >> 4;
    const int rowBase = blockIdx.x * BM;
    float acc[TM][TN];
#pragma unroll
    for (int i = 0; i < TM; ++i)
#pragma unroll
        for (int j = 0; j < TN; ++j) acc[i][j] = 0.f;

    for (int kk = 0; kk < K; kk += BK) {
        // A tile: 64x32 = 512 float4, 2 per thread; store transposed As[k][m]
#pragma unroll
        for (int i = tid; i < (BM * BK) / 4; i += 256) {
            int m  = i >> 3;       // 8 float4 per row of 32
            int kq = i & 7;
            int grow = rowBase + m;
            float4 v = make_float4(0.f, 0.f, 0.f, 0.f);
            if (grow < M) v = *(const float4*)(A + (size_t)grow * K + kk + kq * 4);
            As[kq * 4 + 0][m] = v.x;
            As[kq * 4 + 1][m] = v.y;
            As[kq * 4 + 2][m] = v.z;
            As[kq * 4 + 3][m] = v.w;
        }
        // B tile: BKxBN, straight copy (B row-major stride BN)
#pragma unroll
        for (int i = tid; i < (BK * BN) / 4; i += 256) {
            int k  = i / (BN / 4);
            int n4 = i % (BN / 4);
            *(float4*)&Bs[k][n4 * 4] = *(const float4*)(B + (size_t)(kk + k) * BN + n4 * 4);
        }
        __syncthreads();
#pragma unroll 8
        for (int k = 0; k < BK; ++k) {
            float a[TM], b[TN];
#pragma unroll
            for (int i = 0; i < TM; ++i) a[i] = As[k][ty * TM + i];
#pragma unroll
            for (int j = 0; j < TN; ++j) b[j] = Bs[k][tx * TN + j];
#pragma unroll
            for (int i = 0; i < TM; ++i)
#pragma unroll
                for (int j = 0; j < TN; ++j)
                    acc[i][j] = fmaf(a[i], b[j], acc[i][j]);
        }
        __syncthreads();
    }
#pragma unroll
    for (int i = 0; i < TM; ++i) {
        int grow = rowBase + ty * TM + i;
        if (grow < M) {
#pragma unroll
            for (int j = 0; j < TN; ++j) {
                float v = acc[i][j];
                if (bias) v += bias[tx * TN + j];
                C[(size_t)grow * BN + tx * TN + j] = v;
            }
        }
    }
}

// ---------------- GCN aggregation + bias + relu ----------------
// out[n][f] = relu( dinv[n]*sum_e dinv[src]*h[src][f] + h[n][f]*dinv[n]^2 + b[f] )

__global__ void agg_relu(const float* __restrict__ h, const float* __restrict__ dinv,
                         const int* __restrict__ rowstart, const int* __restrict__ csr,
                         const float* __restrict__ bias, float* __restrict__ out) {
    int n = blockIdx.x;
    int f = threadIdx.x;
    int s = rowstart[n], epos = rowstart[n + 1];
    float acc = 0.f;
    for (int e = s; e < epos; ++e) {
        int sc = csr[e];
        acc = fmaf(dinv[sc], h[(size_t)sc * HID + f], acc);
    }
    float dn = dinv[n];
    float v = acc * dn + h[(size_t)n * HID + f] * dn * dn + bias[f];
    out[(size_t)n * HID + f] = fmaxf(v, 0.f);
}

// ---------------- BatchNorm (training-mode batch stats) ----------------

__global__ void bn_reduce(const float* __restrict__ x, float* __restrict__ acc) {
    int f  = threadIdx.x & 127;
    int rs = threadIdx.x >> 7;
    const int RPB = (N_NODES + gridDim.x - 1) / gridDim.x;
    int r0 = blockIdx.x * RPB;
    int r1 = min(r0 + RPB, N_NODES);
    float s = 0.f, sq = 0.f;
    for (int r = r0 + rs; r < r1; r += 2) {
        float v = x[(size_t)r * HID + f];
        s += v;
        sq = fmaf(v, v, sq);
    }
    atomicAdd(&acc[f], s);
    atomicAdd(&acc[HID + f], sq);
}

__global__ void bn_apply(float* __restrict__ x, const float* __restrict__ acc,
                         const float* __restrict__ gamma, const float* __restrict__ beta) {
    size_t idx = (size_t)blockIdx.x * blockDim.x + threadIdx.x;
    if (idx < (size_t)N_NODES * HID) {
        int f = (int)(idx & 127);
        float mean = acc[f] * (1.0f / N_NODES);
        float var  = fmaxf(acc[HID + f] * (1.0f / N_NODES) - mean * mean, 0.f);
        float sc   = gamma[f] * rsqrtf(var + BN_EPS);
        x[idx] = (x[idx] - mean) * sc + beta[f];
    }
}

// ---------------- attention head ----------------

// G rows: l*8192 + j ; j<4096 -> ids_a[j] else ids_b[j-4096]
__global__ void gather_G(const float* __restrict__ emb0, const float* __restrict__ emb1,
                         const float* __restrict__ emb2,
                         const int* __restrict__ ids_a, const int* __restrict__ ids_b,
                         float* __restrict__ G) {
    size_t idx = (size_t)blockIdx.x * blockDim.x + threadIdx.x;
    const size_t TOT = (size_t)3 * 2 * BATCH * HID;
    if (idx >= TOT) return;
    int f   = (int)(idx & 127);
    int row = (int)(idx >> 7);
    int l   = row / (2 * BATCH);
    int j   = row % (2 * BATCH);
    int node = (j < BATCH) ? ids_a[j] : ids_b[j - BATCH];
    const float* emb = (l == 0) ? emb0 : (l == 1) ? emb1 : emb2;
    G[idx] = emb[(size_t)node * HID + f];
}

// e[r] = sum_k leaky_relu(H[r][k]) * q[k], one wave per row
__global__ void lrelu_dotq(const float* __restrict__ H, const float* __restrict__ q,
                           float* __restrict__ e, int R) {
    int lane = threadIdx.x & 63;
    int wave = threadIdx.x >> 6;
    int r = blockIdx.x * 4 + wave;
    if (r >= R) return;
    float a = 0.f;
#pragma unroll
    for (int t = 0; t < 2; ++t) {
        int k = lane + 64 * t;
        float v = H[(size_t)r * HID + k];
        v = (v > 0.f) ? v : SLOPE * v;
        a = fmaf(v, q[k], a);
    }
    for (int off = 32; off > 0; off >>= 1) a += __shfl_down(a, off, 64);
    if (lane == 0) e[r] = a;
}

// softmax over the 3 layer logits, pool the gathered embeddings
__global__ void softmax_pool(const float* __restrict__ G, const float* __restrict__ e,
                             float* __restrict__ P) {
    int j = blockIdx.x;     // 0..8191
    int f = threadIdx.x;    // 0..127
    float e0 = e[j], e1 = e[2 * BATCH + j], e2 = e[4 * BATCH + j];
    float m = fmaxf(e0, fmaxf(e1, e2));
    float a0 = expf(e0 - m), a1 = expf(e1 - m), a2 = expf(e2 - m);
    float inv = 1.0f / (a0 + a1 + a2);
    float p = a0 * G[((size_t)0 * 2 * BATCH + j) * HID + f]
            + a1 * G[((size_t)1 * 2 * BATCH + j) * HID + f]
            + a2 * G[((size_t)2 * 2 * BATCH + j) * HID + f];
    P[(size_t)j * HID + f] = p * inv;
}

// ---------------- host ----------------

extern "C" void kernel_launch(void* const* d_in, const int* in_sizes, int n_in,
                              void* d_out, int out_size, void* d_ws, size_t ws_size,
                              hipStream_t stream) {
    const float* x          = (const float*)d_in[0];
    const int*   ei         = (const int*)d_in[1];
    const int*   srcp       = ei;
    const int*   dstp       = ei + N_EDGES;
    const int*   drug_pos   = (const int*)d_in[2];
    const int*   target_pos = (const int*)d_in[3];
    const int*   drug_neg   = (const int*)d_in[4];
    const int*   target_neg = (const int*)d_in[5];
    const float* gcn_w[3]   = {(const float*)d_in[7], (const float*)d_in[9], (const float*)d_in[11]};
    const float* gcn_b[3]   = {(const float*)d_in[8], (const float*)d_in[10], (const float*)d_in[12]};
    const float* gamma      = (const float*)d_in[13];
    const float* beta       = (const float*)d_in[14];
    const float* W_D        = (const float*)d_in[15];
    const float* W_T        = (const float*)d_in[16];
    const float* q_D        = (const float*)d_in[17];
    const float* q_T        = (const float*)d_in[18];
    const float* out_w      = (const float*)d_in[19];
    const float* out_b      = (const float*)d_in[20];
    float*       out        = (float*)d_out;

    // ---- carve workspace (~128 MB) ----
    char* p = (char*)d_ws;
    auto alloc = [&](size_t bytes) -> char* {
        char* r = p;
        p += (bytes + 255) & ~(size_t)255;
        return r;
    };
    float* h_buf = (float*)alloc(sizeof(float) * (size_t)N_NODES * HID);   // also reused for G_D/G_T
    float* emb0  = (float*)alloc(sizeof(float) * (size_t)N_NODES * HID);
    float* emb1  = (float*)alloc(sizeof(float) * (size_t)N_NODES * HID);
    float* emb2  = (float*)alloc(sizeof(float) * (size_t)N_NODES * HID);
    float* Hbuf  = (float*)alloc(sizeof(float) * (size_t)3 * 2 * BATCH * HID);
    float* Pbuf  = (float*)alloc(sizeof(float) * (size_t)2 * 2 * BATCH * HID);
    float* ebuf  = (float*)alloc(sizeof(float) * (size_t)2 * 3 * 2 * BATCH);
    float* wt    = (float*)alloc(sizeof(float) * IN_DIM * HID);
    int*   cnt   = (int*)alloc(sizeof(int) * (size_t)2 * N_NODES);  // cnt + cursor, adjacent
    int*   cursor = cnt + N_NODES;
    int*   rowstart = (int*)alloc(sizeof(int) * (N_NODES + 1));
    int*   csr   = (int*)alloc(sizeof(int) * N_EDGES);
    float* dinvp = (float*)alloc(sizeof(float) * N_NODES);
    float* bnacc = (float*)alloc(sizeof(float) * 2 * HID);
    if ((size_t)(p - (char*)d_ws) > ws_size) return;   // visible failure if ws too small

    float* embp[3] = {emb0, emb1, emb2};

    // ---- CSR build (once; reused for all 3 layers) ----
    hipMemsetAsync(cnt, 0, sizeof(int) * (size_t)2 * N_NODES, stream);
    count_deg<<<(N_EDGES + 255) / 256, 256, 0, stream>>>(dstp, cnt);
    scan_kernel<<<1, 1024, 0, stream>>>(cnt, rowstart);
    compute_dinv<<<(N_NODES + 255) / 256, 256, 0, stream>>>(cnt, dinvp);
    scatter_edges<<<(N_EDGES + 255) / 256, 256, 0, stream>>>(srcp, dstp, rowstart, cursor, csr);

    // ---- 3 GCN layers ----
    const float* prev = x;
    int din = IN_DIM;
    for (int l = 0; l < 3; ++l) {
        transpose_k<<<(din * HID + 255) / 256, 256, 0, stream>>>(gcn_w[l], wt, HID, din);
        gemm_kernel<HID, 8><<<dim3((N_NODES + 63) / 64), 256, 0, stream>>>(
            prev, wt, nullptr, h_buf, N_NODES, din);
        agg_relu<<<N_NODES, HID, 0, stream>>>(h_buf, dinvp, rowstart, csr, gcn_b[l], embp[l]);
        hipMemsetAsync(bnacc, 0, sizeof(float) * 2 * HID, stream);
        bn_reduce<<<200, 256, 0, stream>>>(embp[l], bnacc);
        bn_apply<<<((size_t)N_NODES * HID + 255) / 256, 256, 0, stream>>>(embp[l], bnacc, gamma, beta);
        prev = embp[l];
        din = HID;
    }

    // ---- attention pooling on the gathered node set only ----
    const int RG = 3 * 2 * BATCH;   // 24576 gathered rows per pool
    float* G_D = h_buf;
    float* G_T = h_buf + (size_t)RG * HID;
    float* P_D = Pbuf;
    float* P_T = Pbuf + (size_t)2 * BATCH * HID;
    float* e_D = ebuf;
    float* e_T = ebuf + RG;

    gather_G<<<((size_t)RG * HID + 255) / 256, 256, 0, stream>>>(emb0, emb1, emb2, drug_pos, drug_neg, G_D);
    gather_G<<<((size_t)RG * HID + 255) / 256, 256, 0, stream>>>(emb0, emb1, emb2, target_pos, target_neg, G_T);

    // D pool
    transpose_k<<<(HID * HID + 255) / 256, 256, 0, stream>>>(W_D, wt, HID, HID);
    gemm_kernel<HID, 8><<<dim3(RG / 64), 256, 0, stream>>>(G_D, wt, nullptr, Hbuf, RG, HID);
    lrelu_dotq<<<RG / 4, 256, 0, stream>>>(Hbuf, q_D, e_D, RG);
    softmax_pool<<<2 * BATCH, HID, 0, stream>>>(G_D, e_D, P_D);
    // T pool
    transpose_k<<<(HID * HID + 255) / 256, 256, 0, stream>>>(W_T, wt, HID, HID);
    gemm_kernel<HID, 8><<<dim3(RG / 64), 256, 0, stream>>>(G_T, wt, nullptr, Hbuf, RG, HID);
    lrelu_dotq<<<RG / 4, 256, 0, stream>>>(Hbuf, q_T, e_T, RG);
    softmax_pool<<<2 * BATCH, HID, 0, stream>>>(G_T, e_T, P_T);

    // ---- output head: z = P @ out_w^T + out_b, scattered to 4 output slots ----
    transpose_k<<<(OUT_DIM * HID + 255) / 256, 256, 0, stream>>>(out_w, wt, OUT_DIM, HID);
    gemm_kernel<OUT_DIM, 4><<<dim3(BATCH / 64), 256, 0, stream>>>(
        P_D, wt, out_b, out + (size_t)0 * BATCH * OUT_DIM, BATCH, HID);
    gemm_kernel<OUT_DIM, 4><<<dim3(BATCH / 64), 256, 0, stream>>>(
        P_T, wt, out_b, out + (size_t)1 * BATCH * OUT_DIM, BATCH, HID);
    gemm_kernel<OUT_DIM, 4><<<dim3(BATCH / 64), 256, 0, stream>>>(
        P_D + (size_t)BATCH * HID, wt, out_b, out + (size_t)2 * BATCH * OUT_DIM, BATCH, HID);
    gemm_kernel<OUT_DIM, 4><<<dim3(BATCH / 64), 256, 0, stream>>>(
        P_T + (size_t)BATCH * HID, wt, out_b, out + (size_t)3 * BATCH * OUT_DIM, BATCH, HID);
}

// Round 4
// 837.329 us; speedup vs baseline: 1.2250x; 1.2250x over previous
//
#include <hip/hip_runtime.h>
#include <cstdint>

#define N_NODES 50000
#define IN_DIM  256
#define HID     128
#define OUT_DIM 64
#define N_EDGES 800000
#define BATCH   4096
#define BN_EPS  1e-5f
#define SLOPE   0.01f

typedef unsigned short u16;
typedef __attribute__((ext_vector_type(8))) short bf16x8;
typedef __attribute__((ext_vector_type(4))) float f32x4;

__device__ __forceinline__ u16 f2bf(float f) {
    union { float f; unsigned u; } v; v.f = f;
    unsigned r = v.u + 0x7FFF + ((v.u >> 16) & 1);   // RNE
    return (u16)(r >> 16);
}
__device__ __forceinline__ float bf2f(u16 b) {
    union { unsigned u; float f; } v; v.u = ((unsigned)b) << 16;
    return v.f;
}

// ---------------- CSR build ----------------

__global__ void count_deg(const int* __restrict__ dst, int* __restrict__ cnt) {
    int e = blockIdx.x * blockDim.x + threadIdx.x;
    if (e < N_EDGES) atomicAdd(&cnt[dst[e]], 1);
}

__global__ void compute_dinv(const int* __restrict__ cnt, float* __restrict__ dinv) {
    int n = blockIdx.x * blockDim.x + threadIdx.x;
    if (n < N_NODES) dinv[n] = rsqrtf(1.0f + (float)cnt[n]);
}

__global__ void scan_kernel(const int* __restrict__ cnt, int* __restrict__ rowstart) {
    __shared__ int sdata[1024];
    const int CHUNK = (N_NODES + 1023) / 1024;
    int t = threadIdx.x;
    int lo = t * CHUNK;
    int hi = min(lo + CHUNK, N_NODES);
    int loc = 0;
    for (int i = lo; i < hi; ++i) loc += cnt[i];
    sdata[t] = loc;
    __syncthreads();
    for (int off = 1; off < 1024; off <<= 1) {
        int v = (t >= off) ? sdata[t - off] : 0;
        __syncthreads();
        sdata[t] += v;
        __syncthreads();
    }
    int run = sdata[t] - loc;
    for (int i = lo; i < hi; ++i) { rowstart[i] = run; run += cnt[i]; }
    if (t == 1023) rowstart[N_NODES] = sdata[1023];
}

__global__ void scatter_edges(const int* __restrict__ src, const int* __restrict__ dst,
                              const int* __restrict__ rowstart, int* __restrict__ cursor,
                              int* __restrict__ csr) {
    int e = blockIdx.x * blockDim.x + threadIdx.x;
    if (e < N_EDGES) {
        int d = dst[e];
        int pos = rowstart[d] + atomicAdd(&cursor[d], 1);
        csr[pos] = src[e];
    }
}

// ---------------- fp32 -> split bf16 (hi + residual lo) ----------------

__global__ void f32_split_bf16(const float* __restrict__ a, u16* __restrict__ hi,
                               u16* __restrict__ lo, int n) {
    int i = blockIdx.x * blockDim.x + threadIdx.x;
    if (i < n) {
        float v = a[i];
        u16 h = f2bf(v);
        hi[i] = h;
        lo[i] = f2bf(v - bf2f(h));
    }
}

// ---------------- small transpose (fp32, for output head) ----------------

__global__ void transpose_k(const float* __restrict__ W, float* __restrict__ Wt, int R, int C) {
    int idx = blockIdx.x * blockDim.x + threadIdx.x;
    if (idx < R * C) {
        int c = idx / R, r = idx % R;
        Wt[idx] = W[r * C + c];
    }
}

// ---------------- split-bf16 MFMA GEMM: C[M][128](f32) = A[M][K](f32) @ W[128][K]^T ----------
// fp32-grade: A and W each split hi+lo bf16; acc += al*bh + ah*bl + ah*bh (fp32 accum).
// 256 threads = 4 waves; wave w owns rows [w*32, w*32+32); 8 col-tiles of 16.

__global__ __launch_bounds__(256) void mfma_gemm(const float* __restrict__ A,
                                                 const u16* __restrict__ Wh,
                                                 const u16* __restrict__ Wl,
                                                 float* __restrict__ C,
                                                 int M, int K) {
    __shared__ u16 Ah[128][40];   // 32 bf16 + 8 pad
    __shared__ u16 Al[128][40];
    const int tid  = threadIdx.x;
    const int wave = tid >> 6, lane = tid & 63;
    const int lr   = lane & 15, quad = lane >> 4;
    const int rowBase = blockIdx.x * 128;

    f32x4 acc[2][8];
#pragma unroll
    for (int i = 0; i < 2; ++i)
#pragma unroll
        for (int j = 0; j < 8; ++j) acc[i][j] = (f32x4){0.f, 0.f, 0.f, 0.f};

    const int r = tid >> 1, hf = tid & 1;
    const int grow = rowBase + r;

    for (int kk = 0; kk < K; kk += 32) {
        u16 sh[16], sl[16];
        if (grow < M) {
            const float* src = A + (size_t)grow * K + kk + hf * 16;
#pragma unroll
            for (int i = 0; i < 4; ++i) {
                float4 v = ((const float4*)src)[i];
                float vv[4] = {v.x, v.y, v.z, v.w};
#pragma unroll
                for (int c = 0; c < 4; ++c) {
                    u16 h = f2bf(vv[c]);
                    sh[i * 4 + c] = h;
                    sl[i * 4 + c] = f2bf(vv[c] - bf2f(h));
                }
            }
        } else {
#pragma unroll
            for (int i = 0; i < 16; ++i) { sh[i] = 0; sl[i] = 0; }
        }
        *(uint4*)&Ah[r][hf * 16 + 0] = *(uint4*)&sh[0];
        *(uint4*)&Ah[r][hf * 16 + 8] = *(uint4*)&sh[8];
        *(uint4*)&Al[r][hf * 16 + 0] = *(uint4*)&sl[0];
        *(uint4*)&Al[r][hf * 16 + 8] = *(uint4*)&sl[8];
        __syncthreads();

        bf16x8 ah0 = *(const bf16x8*)&Ah[wave * 32 +      lr][quad * 8];
        bf16x8 ah1 = *(const bf16x8*)&Ah[wave * 32 + 16 + lr][quad * 8];
        bf16x8 al0 = *(const bf16x8*)&Al[wave * 32 +      lr][quad * 8];
        bf16x8 al1 = *(const bf16x8*)&Al[wave * 32 + 16 + lr][quad * 8];
#pragma unroll
        for (int ct = 0; ct < 8; ++ct) {
            size_t boff = (size_t)(ct * 16 + lr) * K + kk + quad * 8;
            bf16x8 bh = *(const bf16x8*)(Wh + boff);
            bf16x8 bl = *(const bf16x8*)(Wl + boff);
            acc[0][ct] = __builtin_amdgcn_mfma_f32_16x16x32_bf16(al0, bh, acc[0][ct], 0, 0, 0);
            acc[0][ct] = __builtin_amdgcn_mfma_f32_16x16x32_bf16(ah0, bl, acc[0][ct], 0, 0, 0);
            acc[0][ct] = __builtin_amdgcn_mfma_f32_16x16x32_bf16(ah0, bh, acc[0][ct], 0, 0, 0);
            acc[1][ct] = __builtin_amdgcn_mfma_f32_16x16x32_bf16(al1, bh, acc[1][ct], 0, 0, 0);
            acc[1][ct] = __builtin_amdgcn_mfma_f32_16x16x32_bf16(ah1, bl, acc[1][ct], 0, 0, 0);
            acc[1][ct] = __builtin_amdgcn_mfma_f32_16x16x32_bf16(ah1, bh, acc[1][ct], 0, 0, 0);
        }
        __syncthreads();
    }

#pragma unroll
    for (int rt = 0; rt < 2; ++rt) {
        int row0 = rowBase + wave * 32 + rt * 16 + quad * 4;
#pragma unroll
        for (int reg = 0; reg < 4; ++reg) {
            int row = row0 + reg;
            if (row < M) {
#pragma unroll
                for (int ct = 0; ct < 8; ++ct)
                    C[(size_t)row * 128 + ct * 16 + lr] = acc[rt][ct][reg];
            }
        }
    }
}

// ---------------- GCN aggregation (fp32 gather) + bias + relu ----------------
// One wave per node; lane = 32*ep + q; 2 edges in flight; float4 per lane.

__global__ __launch_bounds__(256) void agg_relu(const float* __restrict__ h,
                                                const float* __restrict__ dinv,
                                                const int* __restrict__ rowstart,
                                                const int* __restrict__ csr,
                                                const float* __restrict__ bias,
                                                float* __restrict__ out) {
    int wave = threadIdx.x >> 6;
    int lane = threadIdx.x & 63;
    int n = blockIdx.x * 4 + wave;
    if (n >= N_NODES) return;
    int ep = lane >> 5;     // 0..1: which edge of the pair
    int q  = lane & 31;     // float4 index within the 128-float row
    int s = rowstart[n], e1 = rowstart[n + 1];
    float ax = 0.f, ay = 0.f, az = 0.f, aw = 0.f;
    for (int e = s + ep; e < e1; e += 2) {
        int sc = csr[e];
        float dv = dinv[sc];
        float4 v = ((const float4*)(h + (size_t)sc * HID))[q];
        ax = fmaf(dv, v.x, ax);
        ay = fmaf(dv, v.y, ay);
        az = fmaf(dv, v.z, az);
        aw = fmaf(dv, v.w, aw);
    }
    // combine the two edge-parallel halves (lane l <-> l^32 hold same q)
    ax += __shfl_xor(ax, 32);
    ay += __shfl_xor(ay, 32);
    az += __shfl_xor(az, 32);
    aw += __shfl_xor(aw, 32);
    if (ep == 0) {
        float dn = dinv[n];
        float dn2 = dn * dn;
        float4 hv = ((const float4*)(h + (size_t)n * HID))[q];
        float4 bv = ((const float4*)bias)[q];
        float4 o;
        o.x = fmaxf(fmaf(ax, dn, fmaf(hv.x, dn2, bv.x)), 0.f);
        o.y = fmaxf(fmaf(ay, dn, fmaf(hv.y, dn2, bv.y)), 0.f);
        o.z = fmaxf(fmaf(az, dn, fmaf(hv.z, dn2, bv.z)), 0.f);
        o.w = fmaxf(fmaf(aw, dn, fmaf(hv.w, dn2, bv.w)), 0.f);
        ((float4*)(out + (size_t)n * HID))[q] = o;
    }
}

// ---------------- BatchNorm (stats from pre-BN values stored in emb, apply in-place) -------

__global__ void bn_reduce(const float* __restrict__ x, float* __restrict__ acc) {
    int f  = threadIdx.x & 127;
    int rs = threadIdx.x >> 7;
    const int RPB = (N_NODES + gridDim.x - 1) / gridDim.x;
    int r0 = blockIdx.x * RPB;
    int r1 = min(r0 + RPB, N_NODES);
    float s = 0.f, sq = 0.f;
    for (int r = r0 + rs; r < r1; r += 2) {
        float v = x[(size_t)r * HID + f];
        s += v;
        sq = fmaf(v, v, sq);
    }
    atomicAdd(&acc[f], s);
    atomicAdd(&acc[HID + f], sq);
}

__global__ void bn_apply(float* __restrict__ x, const float* __restrict__ acc,
                         const float* __restrict__ gamma, const float* __restrict__ beta) {
    size_t idx = (size_t)blockIdx.x * blockDim.x + threadIdx.x;
    if (idx < (size_t)N_NODES * HID) {
        int f = (int)(idx & 127);
        float mean = acc[f] * (1.0f / N_NODES);
        float var  = fmaxf(acc[HID + f] * (1.0f / N_NODES) - mean * mean, 0.f);
        float sc   = gamma[f] * rsqrtf(var + BN_EPS);
        x[idx] = (x[idx] - mean) * sc + beta[f];
    }
}

// ---------------- attention head (fp32) ----------------

__global__ void gather_G(const float* __restrict__ e0, const float* __restrict__ e1,
                         const float* __restrict__ e2,
                         const int* __restrict__ ids_a, const int* __restrict__ ids_b,
                         float* __restrict__ G) {
    int idx = blockIdx.x * blockDim.x + threadIdx.x;   // float4 units
    const int TOT = 3 * 2 * BATCH * (HID / 4);
    if (idx >= TOT) return;
    int q   = idx & 31;
    int row = idx >> 5;
    int l   = row / (2 * BATCH);
    int j   = row % (2 * BATCH);
    int node = (j < BATCH) ? ids_a[j] : ids_b[j - BATCH];
    const float* e = (l == 0) ? e0 : (l == 1) ? e1 : e2;
    ((float4*)G)[idx] = ((const float4*)(e + (size_t)node * HID))[q];
}

__global__ void lrelu_dotq(const float* __restrict__ H, const float* __restrict__ q,
                           float* __restrict__ e, int R) {
    int lane = threadIdx.x & 63;
    int wave = threadIdx.x >> 6;
    int r = blockIdx.x * 4 + wave;
    if (r >= R) return;
    float a = 0.f;
#pragma unroll
    for (int t = 0; t < 2; ++t) {
        int k = lane + 64 * t;
        float v = H[(size_t)r * HID + k];
        v = (v > 0.f) ? v : SLOPE * v;
        a = fmaf(v, q[k], a);
    }
    for (int off = 32; off > 0; off >>= 1) a += __shfl_down(a, off, 64);
    if (lane == 0) e[r] = a;
}

__global__ void softmax_pool(const float* __restrict__ G, const float* __restrict__ e,
                             float* __restrict__ P) {
    int j = blockIdx.x;     // 0..8191
    int f = threadIdx.x;    // 0..127
    float e0 = e[j], e1 = e[2 * BATCH + j], e2 = e[4 * BATCH + j];
    float m = fmaxf(e0, fmaxf(e1, e2));
    float a0 = expf(e0 - m), a1 = expf(e1 - m), a2 = expf(e2 - m);
    float inv = 1.0f / (a0 + a1 + a2);
    float p = a0 * G[((size_t)0 * 2 * BATCH + j) * HID + f]
            + a1 * G[((size_t)1 * 2 * BATCH + j) * HID + f]
            + a2 * G[((size_t)2 * 2 * BATCH + j) * HID + f];
    P[(size_t)j * HID + f] = p * inv;
}

// ---------------- fp32 tiled GEMM (output head): C[M][64] = A[M][128] @ B[128][64] + bias ----

template<int BN, int TN>
__global__ __launch_bounds__(256) void gemm_kernel(const float* __restrict__ A,
                                                   const float* __restrict__ B,
                                                   const float* __restrict__ bias,
                                                   float* __restrict__ C,
                                                   int M, int K) {
    constexpr int BM = 64, BK = 32, TM = 4;
    __shared__ float As[BK][BM];
    __shared__ float Bs[BK][BN];
    const int tid = threadIdx.x;
    const int tx = tid & 15, ty = tid >> 4;
    const int rowBase = blockIdx.x * BM;
    float acc[TM][TN];
#pragma unroll
    for (int i = 0; i < TM; ++i)
#pragma unroll
        for (int j = 0; j < TN; ++j) acc[i][j] = 0.f;

    for (int kk = 0; kk < K; kk += BK) {
#pragma unroll
        for (int i = tid; i < (BM * BK) / 4; i += 256) {
            int m  = i >> 3;
            int kq = i & 7;
            int grow = rowBase + m;
            float4 v = make_float4(0.f, 0.f, 0.f, 0.f);
            if (grow < M) v = *(const float4*)(A + (size_t)grow * K + kk + kq * 4);
            As[kq * 4 + 0][m] = v.x;
            As[kq * 4 + 1][m] = v.y;
            As[kq * 4 + 2][m] = v.z;
            As[kq * 4 + 3][m] = v.w;
        }
#pragma unroll
        for (int i = tid; i < (BK * BN) / 4; i += 256) {
            int k  = i / (BN / 4);
            int n4 = i % (BN / 4);
            *(float4*)&Bs[k][n4 * 4] = *(const float4*)(B + (size_t)(kk + k) * BN + n4 * 4);
        }
        __syncthreads();
#pragma unroll 8
        for (int k = 0; k < BK; ++k) {
            float a[TM], b[TN];
#pragma unroll
            for (int i = 0; i < TM; ++i) a[i] = As[k][ty * TM + i];
#pragma unroll
            for (int j = 0; j < TN; ++j) b[j] = Bs[k][tx * TN + j];
#pragma unroll
            for (int i = 0; i < TM; ++i)
#pragma unroll
                for (int j = 0; j < TN; ++j)
                    acc[i][j] = fmaf(a[i], b[j], acc[i][j]);
        }
        __syncthreads();
    }
#pragma unroll
    for (int i = 0; i < TM; ++i) {
        int grow = rowBase + ty * TM + i;
        if (grow < M) {
#pragma unroll
            for (int j = 0; j < TN; ++j) {
                float v = acc[i][j];
                if (bias) v += bias[tx * TN + j];
                C[(size_t)grow * BN + tx * TN + j] = v;
            }
        }
    }
}

// ---------------- host ----------------

extern "C" void kernel_launch(void* const* d_in, const int* in_sizes, int n_in,
                              void* d_out, int out_size, void* d_ws, size_t ws_size,
                              hipStream_t stream) {
    const float* x          = (const float*)d_in[0];
    const int*   ei         = (const int*)d_in[1];
    const int*   srcp       = ei;
    const int*   dstp       = ei + N_EDGES;
    const int*   drug_pos   = (const int*)d_in[2];
    const int*   target_pos = (const int*)d_in[3];
    const int*   drug_neg   = (const int*)d_in[4];
    const int*   target_neg = (const int*)d_in[5];
    const float* gcn_w[3]   = {(const float*)d_in[7], (const float*)d_in[9], (const float*)d_in[11]};
    const float* gcn_b[3]   = {(const float*)d_in[8], (const float*)d_in[10], (const float*)d_in[12]};
    const float* gamma      = (const float*)d_in[13];
    const float* beta       = (const float*)d_in[14];
    const float* W_D        = (const float*)d_in[15];
    const float* W_T        = (const float*)d_in[16];
    const float* q_D        = (const float*)d_in[17];
    const float* q_T        = (const float*)d_in[18];
    const float* out_w      = (const float*)d_in[19];
    const float* out_b      = (const float*)d_in[20];
    float*       out        = (float*)d_out;

    // ---- carve workspace (~124 MB; proven floor >= 127.6 MB from R3) ----
    char* p = (char*)d_ws;
    auto alloc = [&](size_t bytes) -> char* {
        char* r = p;
        p += (bytes + 255) & ~(size_t)255;
        return r;
    };
    float* hbuf  = (float*)alloc(sizeof(float) * (size_t)N_NODES * HID);   // 25.6 MB; reused as G (25.2)
    float* emb0  = (float*)alloc(sizeof(float) * (size_t)N_NODES * HID);
    float* emb1  = (float*)alloc(sizeof(float) * (size_t)N_NODES * HID);
    float* emb2  = (float*)alloc(sizeof(float) * (size_t)N_NODES * HID);
    float* Pbuf  = (float*)alloc(sizeof(float) * (size_t)2 * 2 * BATCH * HID);
    float* ebuf  = (float*)alloc(sizeof(float) * (size_t)2 * 3 * 2 * BATCH);
    u16*   wh    = (u16*)alloc(sizeof(u16) * HID * IN_DIM);
    u16*   wl    = (u16*)alloc(sizeof(u16) * HID * IN_DIM);
    float* wt    = (float*)alloc(sizeof(float) * OUT_DIM * HID);
    char*  pmark = p;   // ---- union region: graph stuff (layers) | Hbuf (pools) ----
    int*   cnt   = (int*)alloc(sizeof(int) * (size_t)2 * N_NODES);
    int*   cursor = cnt + N_NODES;
    int*   rowstart = (int*)alloc(sizeof(int) * (N_NODES + 1));
    int*   csr   = (int*)alloc(sizeof(int) * N_EDGES);
    float* dinvp = (float*)alloc(sizeof(float) * N_NODES);
    float* bnacc = (float*)alloc(sizeof(float) * 2 * HID);
    char*  pgraph_end = p;
    const int RG = 3 * 2 * BATCH;   // 24576 rows per pool
    float* Hbuf = (float*)pmark;    // 12.6 MB, overlays dead graph buffers in pool phase
    char*  ph_end = pmark + ((sizeof(float) * (size_t)RG * HID + 255) & ~(size_t)255);
    char*  pend = (pgraph_end > ph_end) ? pgraph_end : ph_end;
    if ((size_t)(pend - (char*)d_ws) > ws_size) return;   // visible failure if ws too small

    float* embp[3] = {emb0, emb1, emb2};

    // ---- CSR build (reused for all 3 layers) ----
    hipMemsetAsync(cnt, 0, sizeof(int) * (size_t)2 * N_NODES, stream);
    count_deg<<<(N_EDGES + 255) / 256, 256, 0, stream>>>(dstp, cnt);
    scan_kernel<<<1, 1024, 0, stream>>>(cnt, rowstart);
    compute_dinv<<<(N_NODES + 255) / 256, 256, 0, stream>>>(cnt, dinvp);
    scatter_edges<<<(N_EDGES + 255) / 256, 256, 0, stream>>>(srcp, dstp, rowstart, cursor, csr);

    // ---- 3 GCN layers ----
    const int NB = (N_NODES + 127) / 128;
    for (int l = 0; l < 3; ++l) {
        int din = (l == 0) ? IN_DIM : HID;
        f32_split_bf16<<<(HID * din + 255) / 256, 256, 0, stream>>>(gcn_w[l], wh, wl, HID * din);
        const float* Ain = (l == 0) ? x : embp[l - 1];
        mfma_gemm<<<NB, 256, 0, stream>>>(Ain, wh, wl, hbuf, N_NODES, din);
        agg_relu<<<(N_NODES + 3) / 4, 256, 0, stream>>>(hbuf, dinvp, rowstart, csr, gcn_b[l], embp[l]);
        hipMemsetAsync(bnacc, 0, sizeof(float) * 2 * HID, stream);
        bn_reduce<<<200, 256, 0, stream>>>(embp[l], bnacc);
        bn_apply<<<((size_t)N_NODES * HID + 255) / 256, 256, 0, stream>>>(embp[l], bnacc, gamma, beta);
    }

    // ---- attention pooling on gathered node set (fp32) ----
    float* G_D = hbuf;                       // reuse (h dead after layer 3)
    float* G_T = hbuf + (size_t)RG * HID;
    float* P_D = Pbuf;
    float* P_T = Pbuf + (size_t)2 * BATCH * HID;
    float* e_D = ebuf;
    float* e_T = ebuf + RG;
    const int GU4 = RG * (HID / 4);

    gather_G<<<(GU4 + 255) / 256, 256, 0, stream>>>(emb0, emb1, emb2, drug_pos, drug_neg, G_D);
    gather_G<<<(GU4 + 255) / 256, 256, 0, stream>>>(emb0, emb1, emb2, target_pos, target_neg, G_T);

    // D pool
    f32_split_bf16<<<(HID * HID + 255) / 256, 256, 0, stream>>>(W_D, wh, wl, HID * HID);
    mfma_gemm<<<RG / 128, 256, 0, stream>>>(G_D, wh, wl, Hbuf, RG, HID);
    lrelu_dotq<<<RG / 4, 256, 0, stream>>>(Hbuf, q_D, e_D, RG);
    softmax_pool<<<2 * BATCH, HID, 0, stream>>>(G_D, e_D, P_D);
    // T pool
    f32_split_bf16<<<(HID * HID + 255) / 256, 256, 0, stream>>>(W_T, wh, wl, HID * HID);
    mfma_gemm<<<RG / 128, 256, 0, stream>>>(G_T, wh, wl, Hbuf, RG, HID);
    lrelu_dotq<<<RG / 4, 256, 0, stream>>>(Hbuf, q_T, e_T, RG);
    softmax_pool<<<2 * BATCH, HID, 0, stream>>>(G_T, e_T, P_T);

    // ---- output head ----
    transpose_k<<<(OUT_DIM * HID + 255) / 256, 256, 0, stream>>>(out_w, wt, OUT_DIM, HID);
    gemm_kernel<OUT_DIM, 4><<<BATCH / 64, 256, 0, stream>>>(
        P_D, wt, out_b, out + (size_t)0 * BATCH * OUT_DIM, BATCH, HID);
    gemm_kernel<OUT_DIM, 4><<<BATCH / 64, 256, 0, stream>>>(
        P_T, wt, out_b, out + (size_t)1 * BATCH * OUT_DIM, BATCH, HID);
    gemm_kernel<OUT_DIM, 4><<<BATCH / 64, 256, 0, stream>>>(
        P_D + (size_t)BATCH * HID, wt, out_b, out + (size_t)2 * BATCH * OUT_DIM, BATCH, HID);
    gemm_kernel<OUT_DIM, 4><<<BATCH / 64, 256, 0, stream>>>(
        P_T + (size_t)BATCH * HID, wt, out_b, out + (size_t)3 * BATCH * OUT_DIM, BATCH, HID);
}

// Round 5
// 767.513 us; speedup vs baseline: 1.3364x; 1.0910x over previous
//
#include <hip/hip_runtime.h>
#include <hip/hip_fp16.h>
#include <cstdint>

#define N_NODES 50000
#define IN_DIM  256
#define HID     128
#define OUT_DIM 64
#define N_EDGES 800000
#define BATCH   4096
#define BN_EPS  1e-5f
#define SLOPE   0.01f

typedef unsigned short u16;
typedef __attribute__((ext_vector_type(8))) short bf16x8;
typedef __attribute__((ext_vector_type(4))) float f32x4;

__device__ __forceinline__ u16 f2bf(float f) {
    union { float f; unsigned u; } v; v.f = f;
    unsigned r = v.u + 0x7FFF + ((v.u >> 16) & 1);   // RNE
    return (u16)(r >> 16);
}
__device__ __forceinline__ float bf2f(u16 b) {
    union { unsigned u; float f; } v; v.u = ((unsigned)b) << 16;
    return v.f;
}

// ---------------- CSR build ----------------

__global__ void count_deg(const int* __restrict__ dst, int* __restrict__ cnt) {
    int e = blockIdx.x * blockDim.x + threadIdx.x;
    if (e < N_EDGES) atomicAdd(&cnt[dst[e]], 1);
}

__global__ void compute_dinv(const int* __restrict__ cnt, float* __restrict__ dinv) {
    int n = blockIdx.x * blockDim.x + threadIdx.x;
    if (n < N_NODES) dinv[n] = rsqrtf(1.0f + (float)cnt[n]);
}

// ---- parallel exclusive scan: s1 per-block scan, s2 scan of partials, s3 offset add ----
#define SCAN_NB 196   // 196*256 = 50176 >= 50000

__global__ void scan_s1(const int* __restrict__ cnt, int* __restrict__ rowstart,
                        int* __restrict__ partial) {
    __shared__ int sdata[256];
    int t = threadIdx.x, b = blockIdx.x;
    int i = b * 256 + t;
    int v = (i < N_NODES) ? cnt[i] : 0;
    sdata[t] = v;
    __syncthreads();
#pragma unroll
    for (int off = 1; off < 256; off <<= 1) {
        int tmp = (t >= off) ? sdata[t - off] : 0;
        __syncthreads();
        sdata[t] += tmp;
        __syncthreads();
    }
    if (i < N_NODES) rowstart[i] = sdata[t] - v;   // exclusive
    if (t == 255) partial[b] = sdata[255];
}

__global__ void scan_s2(int* __restrict__ partial, int* __restrict__ rowstart) {
    __shared__ int sdata[256];
    int t = threadIdx.x;
    int v = (t < SCAN_NB) ? partial[t] : 0;
    sdata[t] = v;
    __syncthreads();
#pragma unroll
    for (int off = 1; off < 256; off <<= 1) {
        int tmp = (t >= off) ? sdata[t - off] : 0;
        __syncthreads();
        sdata[t] += tmp;
        __syncthreads();
    }
    if (t < SCAN_NB) partial[t] = sdata[t] - v;    // exclusive block offsets
    if (t == SCAN_NB - 1) rowstart[N_NODES] = sdata[t];
}

__global__ void scan_s3(int* __restrict__ rowstart, const int* __restrict__ partial) {
    int t = threadIdx.x, b = blockIdx.x;
    int i = b * 256 + t;
    if (i < N_NODES) rowstart[i] += partial[b];
}

__global__ void scatter_edges(const int* __restrict__ src, const int* __restrict__ dst,
                              const int* __restrict__ rowstart, int* __restrict__ cursor,
                              int* __restrict__ csr) {
    int e = blockIdx.x * blockDim.x + threadIdx.x;
    if (e < N_EDGES) {
        int d = dst[e];
        int pos = rowstart[d] + atomicAdd(&cursor[d], 1);
        csr[pos] = src[e];
    }
}

// ---------------- fp32 -> split bf16 (hi + residual lo) ----------------

__global__ void f32_split_bf16(const float* __restrict__ a, u16* __restrict__ hi,
                               u16* __restrict__ lo, int n) {
    int i = blockIdx.x * blockDim.x + threadIdx.x;
    if (i < n) {
        float v = a[i];
        u16 h = f2bf(v);
        hi[i] = h;
        lo[i] = f2bf(v - bf2f(h));
    }
}

// split two weights in one launch (W_D then W_T)
__global__ void f32_split_bf16_2(const float* __restrict__ a0, const float* __restrict__ a1,
                                 u16* __restrict__ hi, u16* __restrict__ lo, int n) {
    int i = blockIdx.x * blockDim.x + threadIdx.x;
    if (i < 2 * n) {
        const float* a = (i < n) ? a0 : a1;
        int j = (i < n) ? i : i - n;
        float v = a[j];
        u16 h = f2bf(v);
        hi[i] = h;
        lo[i] = f2bf(v - bf2f(h));
    }
}

__global__ void transpose_k(const float* __restrict__ W, float* __restrict__ Wt, int R, int C) {
    int idx = blockIdx.x * blockDim.x + threadIdx.x;
    if (idx < R * C) {
        int c = idx / R, r = idx % R;
        Wt[idx] = W[r * C + c];
    }
}

// ---------------- split-bf16 MFMA GEMM: C[M][128] = A[M][K](f32) @ W[128][K]^T --------------
// fp32-grade: A and W each split hi+lo bf16; acc += al*bh + ah*bl + ah*bh (fp32 accum).
// OUT_F16: write fp16 (for the gather-heavy aggregation), else fp32.

template<bool OUT_F16>
__global__ __launch_bounds__(256) void mfma_gemm(const float* __restrict__ A,
                                                 const u16* __restrict__ Wh,
                                                 const u16* __restrict__ Wl,
                                                 void* __restrict__ Cout,
                                                 int M, int K) {
    __shared__ u16 Ah[128][40];   // 32 bf16 + 8 pad
    __shared__ u16 Al[128][40];
    const int tid  = threadIdx.x;
    const int wave = tid >> 6, lane = tid & 63;
    const int lr   = lane & 15, quad = lane >> 4;
    const int rowBase = blockIdx.x * 128;

    f32x4 acc[2][8];
#pragma unroll
    for (int i = 0; i < 2; ++i)
#pragma unroll
        for (int j = 0; j < 8; ++j) acc[i][j] = (f32x4){0.f, 0.f, 0.f, 0.f};

    const int r = tid >> 1, hf = tid & 1;
    const int grow = rowBase + r;

    for (int kk = 0; kk < K; kk += 32) {
        u16 sh[16], sl[16];
        if (grow < M) {
            const float* src = A + (size_t)grow * K + kk + hf * 16;
#pragma unroll
            for (int i = 0; i < 4; ++i) {
                float4 v = ((const float4*)src)[i];
                float vv[4] = {v.x, v.y, v.z, v.w};
#pragma unroll
                for (int c = 0; c < 4; ++c) {
                    u16 h = f2bf(vv[c]);
                    sh[i * 4 + c] = h;
                    sl[i * 4 + c] = f2bf(vv[c] - bf2f(h));
                }
            }
        } else {
#pragma unroll
            for (int i = 0; i < 16; ++i) { sh[i] = 0; sl[i] = 0; }
        }
        *(uint4*)&Ah[r][hf * 16 + 0] = *(uint4*)&sh[0];
        *(uint4*)&Ah[r][hf * 16 + 8] = *(uint4*)&sh[8];
        *(uint4*)&Al[r][hf * 16 + 0] = *(uint4*)&sl[0];
        *(uint4*)&Al[r][hf * 16 + 8] = *(uint4*)&sl[8];
        __syncthreads();

        bf16x8 ah0 = *(const bf16x8*)&Ah[wave * 32 +      lr][quad * 8];
        bf16x8 ah1 = *(const bf16x8*)&Ah[wave * 32 + 16 + lr][quad * 8];
        bf16x8 al0 = *(const bf16x8*)&Al[wave * 32 +      lr][quad * 8];
        bf16x8 al1 = *(const bf16x8*)&Al[wave * 32 + 16 + lr][quad * 8];
#pragma unroll
        for (int ct = 0; ct < 8; ++ct) {
            size_t boff = (size_t)(ct * 16 + lr) * K + kk + quad * 8;
            bf16x8 bh = *(const bf16x8*)(Wh + boff);
            bf16x8 bl = *(const bf16x8*)(Wl + boff);
            acc[0][ct] = __builtin_amdgcn_mfma_f32_16x16x32_bf16(al0, bh, acc[0][ct], 0, 0, 0);
            acc[0][ct] = __builtin_amdgcn_mfma_f32_16x16x32_bf16(ah0, bl, acc[0][ct], 0, 0, 0);
            acc[0][ct] = __builtin_amdgcn_mfma_f32_16x16x32_bf16(ah0, bh, acc[0][ct], 0, 0, 0);
            acc[1][ct] = __builtin_amdgcn_mfma_f32_16x16x32_bf16(al1, bh, acc[1][ct], 0, 0, 0);
            acc[1][ct] = __builtin_amdgcn_mfma_f32_16x16x32_bf16(ah1, bl, acc[1][ct], 0, 0, 0);
            acc[1][ct] = __builtin_amdgcn_mfma_f32_16x16x32_bf16(ah1, bh, acc[1][ct], 0, 0, 0);
        }
        __syncthreads();
    }

#pragma unroll
    for (int rt = 0; rt < 2; ++rt) {
        int row0 = rowBase + wave * 32 + rt * 16 + quad * 4;
#pragma unroll
        for (int reg = 0; reg < 4; ++reg) {
            int row = row0 + reg;
            if (row < M) {
#pragma unroll
                for (int ct = 0; ct < 8; ++ct) {
                    if constexpr (OUT_F16) {
                        __half hv = __float2half(acc[rt][ct][reg]);
                        ((u16*)Cout)[(size_t)row * 128 + ct * 16 + lr] = *(u16*)&hv;
                    } else {
                        ((float*)Cout)[(size_t)row * 128 + ct * 16 + lr] = acc[rt][ct][reg];
                    }
                }
            }
        }
    }
}

// ---------------- GCN aggregation (fp16 gather) + bias + relu + fused BN stats ------------
// 256 thr = 4 waves; block covers 64 nodes; lane = 32*ep + q; 2 edges in flight per node.

#define AGG_NPB 64

__global__ __launch_bounds__(256) void agg_relu_bn(const u16* __restrict__ h,
                                                   const float* __restrict__ dinv,
                                                   const int* __restrict__ rowstart,
                                                   const int* __restrict__ csr,
                                                   const float* __restrict__ bias,
                                                   float* __restrict__ out,
                                                   float* __restrict__ bnacc) {
    __shared__ float s_s[HID], s_sq[HID];
    int tid = threadIdx.x;
    if (tid < HID) { s_s[tid] = 0.f; s_sq[tid] = 0.f; }
    __syncthreads();
    int wave = tid >> 6, lane = tid & 63;
    int ep = lane >> 5;     // which edge of the pair
    int q  = lane & 31;     // 4-feature group index (q*4 .. q*4+3)
    int base = blockIdx.x * AGG_NPB;
#pragma unroll 1
    for (int g = 0; g < AGG_NPB / 4; ++g) {
        int n = base + g * 4 + wave;
        if (n < N_NODES) {
            int s = rowstart[n], e1 = rowstart[n + 1];
            float ax = 0.f, ay = 0.f, az = 0.f, aw = 0.f;
            for (int e = s + ep; e < e1; e += 2) {
                int sc = csr[e];
                float dv = dinv[sc];
                uint2 hw = ((const uint2*)(h + (size_t)sc * HID))[q];
                float2 f0 = __half22float2(*(const __half2*)&hw.x);
                float2 f1 = __half22float2(*(const __half2*)&hw.y);
                ax = fmaf(dv, f0.x, ax);
                ay = fmaf(dv, f0.y, ay);
                az = fmaf(dv, f1.x, az);
                aw = fmaf(dv, f1.y, aw);
            }
            ax += __shfl_xor(ax, 32);
            ay += __shfl_xor(ay, 32);
            az += __shfl_xor(az, 32);
            aw += __shfl_xor(aw, 32);
            if (ep == 0) {
                float dn = dinv[n];
                float dn2 = dn * dn;
                uint2 hw = ((const uint2*)(h + (size_t)n * HID))[q];
                float2 h0 = __half22float2(*(const __half2*)&hw.x);
                float2 h1 = __half22float2(*(const __half2*)&hw.y);
                float4 bv = ((const float4*)bias)[q];
                float4 o;
                o.x = fmaxf(fmaf(ax, dn, fmaf(h0.x, dn2, bv.x)), 0.f);
                o.y = fmaxf(fmaf(ay, dn, fmaf(h0.y, dn2, bv.y)), 0.f);
                o.z = fmaxf(fmaf(az, dn, fmaf(h1.x, dn2, bv.z)), 0.f);
                o.w = fmaxf(fmaf(aw, dn, fmaf(h1.y, dn2, bv.w)), 0.f);
                ((float4*)(out + (size_t)n * HID))[q] = o;
                atomicAdd(&s_s[q * 4 + 0], o.x);
                atomicAdd(&s_s[q * 4 + 1], o.y);
                atomicAdd(&s_s[q * 4 + 2], o.z);
                atomicAdd(&s_s[q * 4 + 3], o.w);
                atomicAdd(&s_sq[q * 4 + 0], o.x * o.x);
                atomicAdd(&s_sq[q * 4 + 1], o.y * o.y);
                atomicAdd(&s_sq[q * 4 + 2], o.z * o.z);
                atomicAdd(&s_sq[q * 4 + 3], o.w * o.w);
            }
        }
    }
    __syncthreads();
    if (tid < HID) atomicAdd(&bnacc[tid], s_s[tid]);
    else           atomicAdd(&bnacc[tid], s_sq[tid - HID]);   // tid-HID in [0,128)
}

// ---------------- BatchNorm apply (in-place) ----------------

__global__ void bn_apply(float* __restrict__ x, const float* __restrict__ acc,
                         const float* __restrict__ gamma, const float* __restrict__ beta) {
    size_t idx = (size_t)blockIdx.x * blockDim.x + threadIdx.x;
    if (idx < (size_t)N_NODES * HID) {
        int f = (int)(idx & 127);
        float mean = acc[f] * (1.0f / N_NODES);
        float var  = fmaxf(acc[HID + f] * (1.0f / N_NODES) - mean * mean, 0.f);
        float sc   = gamma[f] * rsqrtf(var + BN_EPS);
        x[idx] = (x[idx] - mean) * sc + beta[f];
    }
}

// ---------------- attention head (fp32), D/T batched via blockIdx.y ----------------

__global__ void gather_G(const float* __restrict__ e0, const float* __restrict__ e1,
                         const float* __restrict__ e2,
                         const int* __restrict__ dpos, const int* __restrict__ dneg,
                         const int* __restrict__ tpos, const int* __restrict__ tneg,
                         float* __restrict__ G_D, float* __restrict__ G_T) {
    int idx = blockIdx.x * blockDim.x + threadIdx.x;   // float4 units
    const int TOT = 3 * 2 * BATCH * (HID / 4);
    if (idx >= TOT) return;
    int q   = idx & 31;
    int row = idx >> 5;
    int l   = row / (2 * BATCH);
    int j   = row % (2 * BATCH);
    const int* ia = blockIdx.y ? tpos : dpos;
    const int* ib = blockIdx.y ? tneg : dneg;
    float* G = blockIdx.y ? G_T : G_D;
    int node = (j < BATCH) ? ia[j] : ib[j - BATCH];
    const float* e = (l == 0) ? e0 : (l == 1) ? e1 : e2;
    ((float4*)G)[idx] = ((const float4*)(e + (size_t)node * HID))[q];
}

__global__ void lrelu_dotq(const float* __restrict__ H_D, const float* __restrict__ H_T,
                           const float* __restrict__ q_D, const float* __restrict__ q_T,
                           float* __restrict__ e_D, float* __restrict__ e_T, int R) {
    int lane = threadIdx.x & 63;
    int wave = threadIdx.x >> 6;
    int r = blockIdx.x * 4 + wave;
    if (r >= R) return;
    const float* H = blockIdx.y ? H_T : H_D;
    const float* q = blockIdx.y ? q_T : q_D;
    float* e = blockIdx.y ? e_T : e_D;
    float a = 0.f;
#pragma unroll
    for (int t = 0; t < 2; ++t) {
        int k = lane + 64 * t;
        float v = H[(size_t)r * HID + k];
        v = (v > 0.f) ? v : SLOPE * v;
        a = fmaf(v, q[k], a);
    }
    for (int off = 32; off > 0; off >>= 1) a += __shfl_down(a, off, 64);
    if (lane == 0) e[r] = a;
}

__global__ void softmax_pool(const float* __restrict__ G_D, const float* __restrict__ G_T,
                             const float* __restrict__ e_D, const float* __restrict__ e_T,
                             float* __restrict__ P_D, float* __restrict__ P_T) {
    int j = blockIdx.x;     // 0..8191
    int f = threadIdx.x;    // 0..127
    const float* G = blockIdx.y ? G_T : G_D;
    const float* e = blockIdx.y ? e_T : e_D;
    float* P = blockIdx.y ? P_T : P_D;
    float e0 = e[j], e1 = e[2 * BATCH + j], e2 = e[4 * BATCH + j];
    float m = fmaxf(e0, fmaxf(e1, e2));
    float a0 = expf(e0 - m), a1 = expf(e1 - m), a2 = expf(e2 - m);
    float inv = 1.0f / (a0 + a1 + a2);
    float p = a0 * G[((size_t)0 * 2 * BATCH + j) * HID + f]
            + a1 * G[((size_t)1 * 2 * BATCH + j) * HID + f]
            + a2 * G[((size_t)2 * 2 * BATCH + j) * HID + f];
    P[(size_t)j * HID + f] = p * inv;
}

// ---------------- output head: 4 segments batched via blockIdx.y ----------------
// y: 0 -> P_D[0:B], 1 -> P_T[0:B], 2 -> P_D[B:2B], 3 -> P_T[B:2B]

__global__ __launch_bounds__(256) void head_gemm(const float* __restrict__ P_D,
                                                 const float* __restrict__ P_T,
                                                 const float* __restrict__ B,
                                                 const float* __restrict__ bias,
                                                 float* __restrict__ out) {
    constexpr int BM = 64, BK = 32, BN = OUT_DIM, TM = 4, TN = 4;
    __shared__ float As[BK][BM];
    __shared__ float Bs[BK][BN];
    const int y = blockIdx.y;
    const float* A = ((y & 1) ? P_T : P_D) + (size_t)(y >> 1) * BATCH * HID;
    float* C = out + (size_t)y * BATCH * OUT_DIM;
    const int tid = threadIdx.x;
    const int tx = tid & 15, ty = tid >> 4;
    const int rowBase = blockIdx.x * BM;
    float acc[TM][TN];
#pragma unroll
    for (int i = 0; i < TM; ++i)
#pragma unroll
        for (int j = 0; j < TN; ++j) acc[i][j] = 0.f;

    for (int kk = 0; kk < HID; kk += BK) {
#pragma unroll
        for (int i = tid; i < (BM * BK) / 4; i += 256) {
            int m  = i >> 3;
            int kq = i & 7;
            float4 v = *(const float4*)(A + (size_t)(rowBase + m) * HID + kk + kq * 4);
            As[kq * 4 + 0][m] = v.x;
            As[kq * 4 + 1][m] = v.y;
            As[kq * 4 + 2][m] = v.z;
            As[kq * 4 + 3][m] = v.w;
        }
#pragma unroll
        for (int i = tid; i < (BK * BN) / 4; i += 256) {
            int k  = i / (BN / 4);
            int n4 = i % (BN / 4);
            *(float4*)&Bs[k][n4 * 4] = *(const float4*)(B + (size_t)(kk + k) * BN + n4 * 4);
        }
        __syncthreads();
#pragma unroll 8
        for (int k = 0; k < BK; ++k) {
            float a[TM], b[TN];
#pragma unroll
            for (int i = 0; i < TM; ++i) a[i] = As[k][ty * TM + i];
#pragma unroll
            for (int j = 0; j < TN; ++j) b[j] = Bs[k][tx * TN + j];
#pragma unroll
            for (int i = 0; i < TM; ++i)
#pragma unroll
                for (int j = 0; j < TN; ++j)
                    acc[i][j] = fmaf(a[i], b[j], acc[i][j]);
        }
        __syncthreads();
    }
#pragma unroll
    for (int i = 0; i < TM; ++i) {
        int grow = rowBase + ty * TM + i;
#pragma unroll
        for (int j = 0; j < TN; ++j)
            C[(size_t)grow * BN + tx * TN + j] = acc[i][j] + bias[tx * TN + j];
    }
}

// ---------------- host ----------------

extern "C" void kernel_launch(void* const* d_in, const int* in_sizes, int n_in,
                              void* d_out, int out_size, void* d_ws, size_t ws_size,
                              hipStream_t stream) {
    const float* x          = (const float*)d_in[0];
    const int*   ei         = (const int*)d_in[1];
    const int*   srcp       = ei;
    const int*   dstp       = ei + N_EDGES;
    const int*   drug_pos   = (const int*)d_in[2];
    const int*   target_pos = (const int*)d_in[3];
    const int*   drug_neg   = (const int*)d_in[4];
    const int*   target_neg = (const int*)d_in[5];
    const float* gcn_w[3]   = {(const float*)d_in[7], (const float*)d_in[9], (const float*)d_in[11]};
    const float* gcn_b[3]   = {(const float*)d_in[8], (const float*)d_in[10], (const float*)d_in[12]};
    const float* gamma      = (const float*)d_in[13];
    const float* beta       = (const float*)d_in[14];
    const float* W_D        = (const float*)d_in[15];
    const float* W_T        = (const float*)d_in[16];
    const float* q_D        = (const float*)d_in[17];
    const float* q_T        = (const float*)d_in[18];
    const float* out_w      = (const float*)d_in[19];
    const float* out_b      = (const float*)d_in[20];
    float*       out        = (float*)d_out;

    // ---- workspace layout (~107 MB) with phase overlays ----
    char* p = (char*)d_ws;
    auto alloc = [&](size_t bytes) -> char* {
        char* r = p;
        p += (bytes + 255) & ~(size_t)255;
        return r;
    };
    // region1 (25.6 MB): phase A = h (fp16, 12.8); phase B = G_D+G_T (fp32, 25.2)
    char*  reg1  = alloc(sizeof(float) * (size_t)N_NODES * HID);
    // region2 (76.8 MB): phase A/gather = emb0..2; post-gather = H_D+H_T | P_D+P_T
    float* emb0  = (float*)alloc(sizeof(float) * (size_t)N_NODES * HID);
    float* emb1  = (float*)alloc(sizeof(float) * (size_t)N_NODES * HID);
    float* emb2  = (float*)alloc(sizeof(float) * (size_t)N_NODES * HID);
    // region3: persistent small stuff
    float* ebuf  = (float*)alloc(sizeof(float) * (size_t)2 * 3 * 2 * BATCH);
    u16*   wh    = (u16*)alloc(sizeof(u16) * HID * IN_DIM);
    u16*   wl    = (u16*)alloc(sizeof(u16) * HID * IN_DIM);
    u16*   whDT  = (u16*)alloc(sizeof(u16) * 2 * HID * HID);
    u16*   wlDT  = (u16*)alloc(sizeof(u16) * 2 * HID * HID);
    float* wt    = (float*)alloc(sizeof(float) * OUT_DIM * HID);
    int*   cnt   = (int*)alloc(sizeof(int) * (size_t)2 * N_NODES);
    int*   cursor = cnt + N_NODES;
    int*   rowstart = (int*)alloc(sizeof(int) * (N_NODES + 1));
    int*   csr   = (int*)alloc(sizeof(int) * N_EDGES);
    float* dinvp = (float*)alloc(sizeof(float) * N_NODES);
    int*   partial = (int*)alloc(sizeof(int) * 256);
    float* bnacc = (float*)alloc(sizeof(float) * 2 * HID);
    if ((size_t)(p - (char*)d_ws) > ws_size) return;   // visible failure if ws too small

    u16*   hbuf = (u16*)reg1;
    const int RG = 3 * 2 * BATCH;   // 24576 rows per pool
    float* G_D  = (float*)reg1;
    float* G_T  = G_D + (size_t)RG * HID;          // 2*12.58 MB <= 25.6 MB
    float* H_D  = emb0;                            // overlays emb (dead after gather)
    float* H_T  = H_D + (size_t)RG * HID;
    float* P_D  = emb1;
    float* P_T  = P_D + (size_t)2 * BATCH * HID;
    float* e_D  = ebuf;
    float* e_T  = ebuf + RG;
    float* embp[3] = {emb0, emb1, emb2};

    // ---- CSR build ----
    hipMemsetAsync(cnt, 0, sizeof(int) * (size_t)2 * N_NODES, stream);
    count_deg<<<(N_EDGES + 255) / 256, 256, 0, stream>>>(dstp, cnt);
    scan_s1<<<SCAN_NB, 256, 0, stream>>>(cnt, rowstart, partial);
    scan_s2<<<1, 256, 0, stream>>>(partial, rowstart);
    scan_s3<<<SCAN_NB, 256, 0, stream>>>(rowstart, partial);
    compute_dinv<<<(N_NODES + 255) / 256, 256, 0, stream>>>(cnt, dinvp);
    scatter_edges<<<(N_EDGES + 255) / 256, 256, 0, stream>>>(srcp, dstp, rowstart, cursor, csr);

    // ---- 3 GCN layers ----
    const int NB = (N_NODES + 127) / 128;
    for (int l = 0; l < 3; ++l) {
        int din = (l == 0) ? IN_DIM : HID;
        f32_split_bf16<<<(HID * din + 255) / 256, 256, 0, stream>>>(gcn_w[l], wh, wl, HID * din);
        const float* Ain = (l == 0) ? x : embp[l - 1];
        mfma_gemm<true><<<NB, 256, 0, stream>>>(Ain, wh, wl, hbuf, N_NODES, din);
        hipMemsetAsync(bnacc, 0, sizeof(float) * 2 * HID, stream);
        agg_relu_bn<<<(N_NODES + AGG_NPB - 1) / AGG_NPB, 256, 0, stream>>>(
            hbuf, dinvp, rowstart, csr, gcn_b[l], embp[l], bnacc);
        bn_apply<<<((size_t)N_NODES * HID + 255) / 256, 256, 0, stream>>>(embp[l], bnacc, gamma, beta);
    }

    // ---- attention pooling (fp32) ----
    const int GU4 = RG * (HID / 4);
    gather_G<<<dim3((GU4 + 255) / 256, 2), 256, 0, stream>>>(
        emb0, emb1, emb2, drug_pos, drug_neg, target_pos, target_neg, G_D, G_T);

    f32_split_bf16_2<<<(2 * HID * HID + 255) / 256, 256, 0, stream>>>(W_D, W_T, whDT, wlDT, HID * HID);
    mfma_gemm<false><<<RG / 128, 256, 0, stream>>>(G_D, whDT, wlDT, H_D, RG, HID);
    mfma_gemm<false><<<RG / 128, 256, 0, stream>>>(G_T, whDT + HID * HID, wlDT + HID * HID, H_T, RG, HID);
    lrelu_dotq<<<dim3(RG / 4, 2), 256, 0, stream>>>(H_D, H_T, q_D, q_T, e_D, e_T, RG);
    softmax_pool<<<dim3(2 * BATCH, 2), HID, 0, stream>>>(G_D, G_T, e_D, e_T, P_D, P_T);

    // ---- output head ----
    transpose_k<<<(OUT_DIM * HID + 255) / 256, 256, 0, stream>>>(out_w, wt, OUT_DIM, HID);
    head_gemm<<<dim3(BATCH / 64, 4), 256, 0, stream>>>(P_D, P_T, wt, out_b, out);
}

// Round 6
// 648.309 us; speedup vs baseline: 1.5822x; 1.1839x over previous
//
#include <hip/hip_runtime.h>
#include <hip/hip_fp16.h>
#include <cstdint>

#define N_NODES 50000
#define IN_DIM  256
#define HID     128
#define OUT_DIM 64
#define N_EDGES 800000
#define BATCH   4096
#define BN_EPS  1e-5f
#define SLOPE   0.01f

typedef unsigned short u16;
typedef __attribute__((ext_vector_type(8))) short bf16x8;
typedef __attribute__((ext_vector_type(4))) float f32x4;

__device__ __forceinline__ u16 f2bf(float f) {
    union { float f; unsigned u; } v; v.f = f;
    unsigned r = v.u + 0x7FFF + ((v.u >> 16) & 1);   // RNE
    return (u16)(r >> 16);
}
__device__ __forceinline__ float bf2f(u16 b) {
    union { unsigned u; float f; } v; v.u = ((unsigned)b) << 16;
    return v.f;
}

// ---------------- CSR build ----------------

__global__ void count_deg(const int* __restrict__ dst, int* __restrict__ cnt) {
    int e = blockIdx.x * blockDim.x + threadIdx.x;
    if (e < N_EDGES) atomicAdd(&cnt[dst[e]], 1);
}

// ---- parallel exclusive scan: s1 per-block scan, s2 scan of partials, s3 offset+dinv ----
#define SCAN_NB 196   // 196*256 = 50176 >= 50000

__global__ void scan_s1(const int* __restrict__ cnt, int* __restrict__ rowstart,
                        int* __restrict__ partial) {
    __shared__ int sdata[256];
    int t = threadIdx.x, b = blockIdx.x;
    int i = b * 256 + t;
    int v = (i < N_NODES) ? cnt[i] : 0;
    sdata[t] = v;
    __syncthreads();
#pragma unroll
    for (int off = 1; off < 256; off <<= 1) {
        int tmp = (t >= off) ? sdata[t - off] : 0;
        __syncthreads();
        sdata[t] += tmp;
        __syncthreads();
    }
    if (i < N_NODES) rowstart[i] = sdata[t] - v;   // exclusive
    if (t == 255) partial[b] = sdata[255];
}

__global__ void scan_s2(int* __restrict__ partial, int* __restrict__ rowstart) {
    __shared__ int sdata[256];
    int t = threadIdx.x;
    int v = (t < SCAN_NB) ? partial[t] : 0;
    sdata[t] = v;
    __syncthreads();
#pragma unroll
    for (int off = 1; off < 256; off <<= 1) {
        int tmp = (t >= off) ? sdata[t - off] : 0;
        __syncthreads();
        sdata[t] += tmp;
        __syncthreads();
    }
    if (t < SCAN_NB) partial[t] = sdata[t] - v;    // exclusive block offsets
    if (t == SCAN_NB - 1) rowstart[N_NODES] = sdata[t];
}

__global__ void scan_s3_dinv(int* __restrict__ rowstart, const int* __restrict__ partial,
                             const int* __restrict__ cnt, float* __restrict__ dinv) {
    int t = threadIdx.x, b = blockIdx.x;
    int i = b * 256 + t;
    if (i < N_NODES) {
        rowstart[i] += partial[b];
        dinv[i] = rsqrtf(1.0f + (float)cnt[i]);
    }
}

__global__ void scatter_edges(const int* __restrict__ src, const int* __restrict__ dst,
                              const int* __restrict__ rowstart, int* __restrict__ cursor,
                              int* __restrict__ csr) {
    int e = blockIdx.x * blockDim.x + threadIdx.x;
    if (e < N_EDGES) {
        int d = dst[e];
        int pos = rowstart[d] + atomicAdd(&cursor[d], 1);
        csr[pos] = src[e];
    }
}

// ---------------- fp32 -> split bf16 (hi + residual lo) ----------------

__global__ void f32_split_bf16(const float* __restrict__ a, u16* __restrict__ hi,
                               u16* __restrict__ lo, int n) {
    int i = blockIdx.x * blockDim.x + threadIdx.x;
    if (i < n) {
        float v = a[i];
        u16 h = f2bf(v);
        hi[i] = h;
        lo[i] = f2bf(v - bf2f(h));
    }
}

// split two weights in one launch (W_D then W_T)
__global__ void f32_split_bf16_2(const float* __restrict__ a0, const float* __restrict__ a1,
                                 u16* __restrict__ hi, u16* __restrict__ lo, int n) {
    int i = blockIdx.x * blockDim.x + threadIdx.x;
    if (i < 2 * n) {
        const float* a = (i < n) ? a0 : a1;
        int j = (i < n) ? i : i - n;
        float v = a[j];
        u16 h = f2bf(v);
        hi[i] = h;
        lo[i] = f2bf(v - bf2f(h));
    }
}

__global__ void transpose_k(const float* __restrict__ W, float* __restrict__ Wt, int R, int C) {
    int idx = blockIdx.x * blockDim.x + threadIdx.x;
    if (idx < R * C) {
        int c = idx / R, r = idx % R;
        Wt[idx] = W[r * C + c];
    }
}

// ---------------- split-bf16 MFMA GEMM: C[M][128] = A[M][K](f32) @ W[128][K]^T --------------
// fp32-grade: A and W each split hi+lo bf16; acc += al*bh + ah*bl + ah*bh (fp32 accum).
// OUT_F16: write fp16 (for the gather-heavy aggregation), else fp32.

template<bool OUT_F16>
__global__ __launch_bounds__(256) void mfma_gemm(const float* __restrict__ A,
                                                 const u16* __restrict__ Wh,
                                                 const u16* __restrict__ Wl,
                                                 void* __restrict__ Cout,
                                                 int M, int K) {
    __shared__ u16 Ah[128][40];   // 32 bf16 + 8 pad
    __shared__ u16 Al[128][40];
    const int tid  = threadIdx.x;
    const int wave = tid >> 6, lane = tid & 63;
    const int lr   = lane & 15, quad = lane >> 4;
    const int rowBase = blockIdx.x * 128;

    f32x4 acc[2][8];
#pragma unroll
    for (int i = 0; i < 2; ++i)
#pragma unroll
        for (int j = 0; j < 8; ++j) acc[i][j] = (f32x4){0.f, 0.f, 0.f, 0.f};

    const int r = tid >> 1, hf = tid & 1;
    const int grow = rowBase + r;

    for (int kk = 0; kk < K; kk += 32) {
        u16 sh[16], sl[16];
        if (grow < M) {
            const float* src = A + (size_t)grow * K + kk + hf * 16;
#pragma unroll
            for (int i = 0; i < 4; ++i) {
                float4 v = ((const float4*)src)[i];
                float vv[4] = {v.x, v.y, v.z, v.w};
#pragma unroll
                for (int c = 0; c < 4; ++c) {
                    u16 h = f2bf(vv[c]);
                    sh[i * 4 + c] = h;
                    sl[i * 4 + c] = f2bf(vv[c] - bf2f(h));
                }
            }
        } else {
#pragma unroll
            for (int i = 0; i < 16; ++i) { sh[i] = 0; sl[i] = 0; }
        }
        *(uint4*)&Ah[r][hf * 16 + 0] = *(uint4*)&sh[0];
        *(uint4*)&Ah[r][hf * 16 + 8] = *(uint4*)&sh[8];
        *(uint4*)&Al[r][hf * 16 + 0] = *(uint4*)&sl[0];
        *(uint4*)&Al[r][hf * 16 + 8] = *(uint4*)&sl[8];
        __syncthreads();

        bf16x8 ah0 = *(const bf16x8*)&Ah[wave * 32 +      lr][quad * 8];
        bf16x8 ah1 = *(const bf16x8*)&Ah[wave * 32 + 16 + lr][quad * 8];
        bf16x8 al0 = *(const bf16x8*)&Al[wave * 32 +      lr][quad * 8];
        bf16x8 al1 = *(const bf16x8*)&Al[wave * 32 + 16 + lr][quad * 8];
#pragma unroll
        for (int ct = 0; ct < 8; ++ct) {
            size_t boff = (size_t)(ct * 16 + lr) * K + kk + quad * 8;
            bf16x8 bh = *(const bf16x8*)(Wh + boff);
            bf16x8 bl = *(const bf16x8*)(Wl + boff);
            acc[0][ct] = __builtin_amdgcn_mfma_f32_16x16x32_bf16(al0, bh, acc[0][ct], 0, 0, 0);
            acc[0][ct] = __builtin_amdgcn_mfma_f32_16x16x32_bf16(ah0, bl, acc[0][ct], 0, 0, 0);
            acc[0][ct] = __builtin_amdgcn_mfma_f32_16x16x32_bf16(ah0, bh, acc[0][ct], 0, 0, 0);
            acc[1][ct] = __builtin_amdgcn_mfma_f32_16x16x32_bf16(al1, bh, acc[1][ct], 0, 0, 0);
            acc[1][ct] = __builtin_amdgcn_mfma_f32_16x16x32_bf16(ah1, bl, acc[1][ct], 0, 0, 0);
            acc[1][ct] = __builtin_amdgcn_mfma_f32_16x16x32_bf16(ah1, bh, acc[1][ct], 0, 0, 0);
        }
        __syncthreads();
    }

#pragma unroll
    for (int rt = 0; rt < 2; ++rt) {
        int row0 = rowBase + wave * 32 + rt * 16 + quad * 4;
#pragma unroll
        for (int reg = 0; reg < 4; ++reg) {
            int row = row0 + reg;
            if (row < M) {
#pragma unroll
                for (int ct = 0; ct < 8; ++ct) {
                    if constexpr (OUT_F16) {
                        __half hv = __float2half(acc[rt][ct][reg]);
                        ((u16*)Cout)[(size_t)row * 128 + ct * 16 + lr] = *(u16*)&hv;
                    } else {
                        ((float*)Cout)[(size_t)row * 128 + ct * 16 + lr] = acc[rt][ct][reg];
                    }
                }
            }
        }
    }
}

// ---------------- GCN aggregation (fp16 gather) + bias + relu -> fp32 pre-BN --------------
// 1 node per wave, 4 waves/block, 12500 blocks. lane = 32*ep + q; edge loop unrolled x2
// per lane-half -> 4 independent csr->row chains in flight per wave.

__global__ __launch_bounds__(256) void agg_relu(const u16* __restrict__ h,
                                                const float* __restrict__ dinv,
                                                const int* __restrict__ rowstart,
                                                const int* __restrict__ csr,
                                                const float* __restrict__ bias,
                                                float* __restrict__ out) {
    int wave = threadIdx.x >> 6;
    int lane = threadIdx.x & 63;
    int n = blockIdx.x * 4 + wave;
    if (n >= N_NODES) return;
    int ep = lane >> 5;     // which edge of the pair
    int q  = lane & 31;     // 4-feature group (q*4 .. q*4+3)
    int s = rowstart[n], e1 = rowstart[n + 1];
    float ax = 0.f, ay = 0.f, az = 0.f, aw = 0.f;
    int e = s + ep;
    for (; e + 2 < e1; e += 4) {
        int sc0 = csr[e];
        int sc1 = csr[e + 2];
        float dv0 = dinv[sc0];
        float dv1 = dinv[sc1];
        uint2 w0 = ((const uint2*)(h + (size_t)sc0 * HID))[q];
        uint2 w1 = ((const uint2*)(h + (size_t)sc1 * HID))[q];
        float2 a0 = __half22float2(*(const __half2*)&w0.x);
        float2 b0 = __half22float2(*(const __half2*)&w0.y);
        float2 a1 = __half22float2(*(const __half2*)&w1.x);
        float2 b1 = __half22float2(*(const __half2*)&w1.y);
        ax = fmaf(dv0, a0.x, ax); ay = fmaf(dv0, a0.y, ay);
        az = fmaf(dv0, b0.x, az); aw = fmaf(dv0, b0.y, aw);
        ax = fmaf(dv1, a1.x, ax); ay = fmaf(dv1, a1.y, ay);
        az = fmaf(dv1, b1.x, az); aw = fmaf(dv1, b1.y, aw);
    }
    if (e < e1) {
        int sc = csr[e];
        float dv = dinv[sc];
        uint2 w0 = ((const uint2*)(h + (size_t)sc * HID))[q];
        float2 a0 = __half22float2(*(const __half2*)&w0.x);
        float2 b0 = __half22float2(*(const __half2*)&w0.y);
        ax = fmaf(dv, a0.x, ax); ay = fmaf(dv, a0.y, ay);
        az = fmaf(dv, b0.x, az); aw = fmaf(dv, b0.y, aw);
    }
    ax += __shfl_xor(ax, 32);
    ay += __shfl_xor(ay, 32);
    az += __shfl_xor(az, 32);
    aw += __shfl_xor(aw, 32);
    if (ep == 0) {
        float dn = dinv[n];
        float dn2 = dn * dn;
        uint2 hw = ((const uint2*)(h + (size_t)n * HID))[q];
        float2 h0 = __half22float2(*(const __half2*)&hw.x);
        float2 h1 = __half22float2(*(const __half2*)&hw.y);
        float4 bv = ((const float4*)bias)[q];
        float4 o;
        o.x = fmaxf(fmaf(ax, dn, fmaf(h0.x, dn2, bv.x)), 0.f);
        o.y = fmaxf(fmaf(ay, dn, fmaf(h0.y, dn2, bv.y)), 0.f);
        o.z = fmaxf(fmaf(az, dn, fmaf(h1.x, dn2, bv.z)), 0.f);
        o.w = fmaxf(fmaf(aw, dn, fmaf(h1.y, dn2, bv.w)), 0.f);
        ((float4*)(out + (size_t)n * HID))[q] = o;
    }
}

// ---------------- BatchNorm ----------------

__global__ void bn_reduce(const float* __restrict__ x, float* __restrict__ acc) {
    int f  = threadIdx.x & 127;
    int rs = threadIdx.x >> 7;
    const int RPB = (N_NODES + gridDim.x - 1) / gridDim.x;
    int r0 = blockIdx.x * RPB;
    int r1 = min(r0 + RPB, N_NODES);
    float s = 0.f, sq = 0.f;
    for (int r = r0 + rs; r < r1; r += 2) {
        float v = x[(size_t)r * HID + f];
        s += v;
        sq = fmaf(v, v, sq);
    }
    atomicAdd(&acc[f], s);
    atomicAdd(&acc[HID + f], sq);
}

__global__ void bn_apply(float* __restrict__ x, const float* __restrict__ acc,
                         const float* __restrict__ gamma, const float* __restrict__ beta) {
    size_t idx = (size_t)blockIdx.x * blockDim.x + threadIdx.x;
    if (idx < (size_t)N_NODES * HID) {
        int f = (int)(idx & 127);
        float mean = acc[f] * (1.0f / N_NODES);
        float var  = fmaxf(acc[HID + f] * (1.0f / N_NODES) - mean * mean, 0.f);
        float sc   = gamma[f] * rsqrtf(var + BN_EPS);
        x[idx] = (x[idx] - mean) * sc + beta[f];
    }
}

// ---------------- attention head (fp32), D/T batched via blockIdx.y ----------------

__global__ void gather_G(const float* __restrict__ e0, const float* __restrict__ e1,
                         const float* __restrict__ e2,
                         const int* __restrict__ dpos, const int* __restrict__ dneg,
                         const int* __restrict__ tpos, const int* __restrict__ tneg,
                         float* __restrict__ G_D, float* __restrict__ G_T) {
    int idx = blockIdx.x * blockDim.x + threadIdx.x;   // float4 units
    const int TOT = 3 * 2 * BATCH * (HID / 4);
    if (idx >= TOT) return;
    int q   = idx & 31;
    int row = idx >> 5;
    int l   = row / (2 * BATCH);
    int j   = row % (2 * BATCH);
    const int* ia = blockIdx.y ? tpos : dpos;
    const int* ib = blockIdx.y ? tneg : dneg;
    float* G = blockIdx.y ? G_T : G_D;
    int node = (j < BATCH) ? ia[j] : ib[j - BATCH];
    const float* e = (l == 0) ? e0 : (l == 1) ? e1 : e2;
    ((float4*)G)[idx] = ((const float4*)(e + (size_t)node * HID))[q];
}

__global__ void lrelu_dotq(const float* __restrict__ H_D, const float* __restrict__ H_T,
                           const float* __restrict__ q_D, const float* __restrict__ q_T,
                           float* __restrict__ e_D, float* __restrict__ e_T, int R) {
    int lane = threadIdx.x & 63;
    int wave = threadIdx.x >> 6;
    int r = blockIdx.x * 4 + wave;
    if (r >= R) return;
    const float* H = blockIdx.y ? H_T : H_D;
    const float* q = blockIdx.y ? q_T : q_D;
    float* e = blockIdx.y ? e_T : e_D;
    float a = 0.f;
#pragma unroll
    for (int t = 0; t < 2; ++t) {
        int k = lane + 64 * t;
        float v = H[(size_t)r * HID + k];
        v = (v > 0.f) ? v : SLOPE * v;
        a = fmaf(v, q[k], a);
    }
    for (int off = 32; off > 0; off >>= 1) a += __shfl_down(a, off, 64);
    if (lane == 0) e[r] = a;
}

__global__ void softmax_pool(const float* __restrict__ G_D, const float* __restrict__ G_T,
                             const float* __restrict__ e_D, const float* __restrict__ e_T,
                             float* __restrict__ P_D, float* __restrict__ P_T) {
    int j = blockIdx.x;     // 0..8191
    int f = threadIdx.x;    // 0..127
    const float* G = blockIdx.y ? G_T : G_D;
    const float* e = blockIdx.y ? e_T : e_D;
    float* P = blockIdx.y ? P_T : P_D;
    float e0 = e[j], e1 = e[2 * BATCH + j], e2 = e[4 * BATCH + j];
    float m = fmaxf(e0, fmaxf(e1, e2));
    float a0 = expf(e0 - m), a1 = expf(e1 - m), a2 = expf(e2 - m);
    float inv = 1.0f / (a0 + a1 + a2);
    float p = a0 * G[((size_t)0 * 2 * BATCH + j) * HID + f]
            + a1 * G[((size_t)1 * 2 * BATCH + j) * HID + f]
            + a2 * G[((size_t)2 * 2 * BATCH + j) * HID + f];
    P[(size_t)j * HID + f] = p * inv;
}

// ---------------- output head: 4 segments batched via blockIdx.y ----------------

__global__ __launch_bounds__(256) void head_gemm(const float* __restrict__ P_D,
                                                 const float* __restrict__ P_T,
                                                 const float* __restrict__ B,
                                                 const float* __restrict__ bias,
                                                 float* __restrict__ out) {
    constexpr int BM = 64, BK = 32, BN = OUT_DIM, TM = 4, TN = 4;
    __shared__ float As[BK][BM];
    __shared__ float Bs[BK][BN];
    const int y = blockIdx.y;
    const float* A = ((y & 1) ? P_T : P_D) + (size_t)(y >> 1) * BATCH * HID;
    float* C = out + (size_t)y * BATCH * OUT_DIM;
    const int tid = threadIdx.x;
    const int tx = tid & 15, ty = tid >> 4;
    const int rowBase = blockIdx.x * BM;
    float acc[TM][TN];
#pragma unroll
    for (int i = 0; i < TM; ++i)
#pragma unroll
        for (int j = 0; j < TN; ++j) acc[i][j] = 0.f;

    for (int kk = 0; kk < HID; kk += BK) {
#pragma unroll
        for (int i = tid; i < (BM * BK) / 4; i += 256) {
            int m  = i >> 3;
            int kq = i & 7;
            float4 v = *(const float4*)(A + (size_t)(rowBase + m) * HID + kk + kq * 4);
            As[kq * 4 + 0][m] = v.x;
            As[kq * 4 + 1][m] = v.y;
            As[kq * 4 + 2][m] = v.z;
            As[kq * 4 + 3][m] = v.w;
        }
#pragma unroll
        for (int i = tid; i < (BK * BN) / 4; i += 256) {
            int k  = i / (BN / 4);
            int n4 = i % (BN / 4);
            *(float4*)&Bs[k][n4 * 4] = *(const float4*)(B + (size_t)(kk + k) * BN + n4 * 4);
        }
        __syncthreads();
#pragma unroll 8
        for (int k = 0; k < BK; ++k) {
            float a[TM], b[TN];
#pragma unroll
            for (int i = 0; i < TM; ++i) a[i] = As[k][ty * TM + i];
#pragma unroll
            for (int j = 0; j < TN; ++j) b[j] = Bs[k][tx * TN + j];
#pragma unroll
            for (int i = 0; i < TM; ++i)
#pragma unroll
                for (int j = 0; j < TN; ++j)
                    acc[i][j] = fmaf(a[i], b[j], acc[i][j]);
        }
        __syncthreads();
    }
#pragma unroll
    for (int i = 0; i < TM; ++i) {
        int grow = rowBase + ty * TM + i;
#pragma unroll
        for (int j = 0; j < TN; ++j)
            C[(size_t)grow * BN + tx * TN + j] = acc[i][j] + bias[tx * TN + j];
    }
}

// ---------------- host ----------------

extern "C" void kernel_launch(void* const* d_in, const int* in_sizes, int n_in,
                              void* d_out, int out_size, void* d_ws, size_t ws_size,
                              hipStream_t stream) {
    const float* x          = (const float*)d_in[0];
    const int*   ei         = (const int*)d_in[1];
    const int*   srcp       = ei;
    const int*   dstp       = ei + N_EDGES;
    const int*   drug_pos   = (const int*)d_in[2];
    const int*   target_pos = (const int*)d_in[3];
    const int*   drug_neg   = (const int*)d_in[4];
    const int*   target_neg = (const int*)d_in[5];
    const float* gcn_w[3]   = {(const float*)d_in[7], (const float*)d_in[9], (const float*)d_in[11]};
    const float* gcn_b[3]   = {(const float*)d_in[8], (const float*)d_in[10], (const float*)d_in[12]};
    const float* gamma      = (const float*)d_in[13];
    const float* beta       = (const float*)d_in[14];
    const float* W_D        = (const float*)d_in[15];
    const float* W_T        = (const float*)d_in[16];
    const float* q_D        = (const float*)d_in[17];
    const float* q_T        = (const float*)d_in[18];
    const float* out_w      = (const float*)d_in[19];
    const float* out_b      = (const float*)d_in[20];
    float*       out        = (float*)d_out;

    // ---- workspace layout (~107 MB) with phase overlays ----
    char* p = (char*)d_ws;
    auto alloc = [&](size_t bytes) -> char* {
        char* r = p;
        p += (bytes + 255) & ~(size_t)255;
        return r;
    };
    // region1 (25.6 MB): phase A = h (fp16, 12.8); phase B = G_D+G_T (fp32, 25.2)
    char*  reg1  = alloc(sizeof(float) * (size_t)N_NODES * HID);
    // region2 (76.8 MB): layers = emb0..2; post-gather overlays = H_D/H_T, P_D/P_T
    float* emb0  = (float*)alloc(sizeof(float) * (size_t)N_NODES * HID);
    float* emb1  = (float*)alloc(sizeof(float) * (size_t)N_NODES * HID);
    float* emb2  = (float*)alloc(sizeof(float) * (size_t)N_NODES * HID);
    // region3: persistent small stuff
    float* ebuf  = (float*)alloc(sizeof(float) * (size_t)2 * 3 * 2 * BATCH);
    u16*   wh    = (u16*)alloc(sizeof(u16) * HID * IN_DIM);
    u16*   wl    = (u16*)alloc(sizeof(u16) * HID * IN_DIM);
    u16*   whDT  = (u16*)alloc(sizeof(u16) * 2 * HID * HID);
    u16*   wlDT  = (u16*)alloc(sizeof(u16) * 2 * HID * HID);
    float* wt    = (float*)alloc(sizeof(float) * OUT_DIM * HID);
    int*   cnt   = (int*)alloc(sizeof(int) * (size_t)2 * N_NODES);
    int*   cursor = cnt + N_NODES;
    int*   rowstart = (int*)alloc(sizeof(int) * (N_NODES + 1));
    int*   csr   = (int*)alloc(sizeof(int) * N_EDGES);
    float* dinvp = (float*)alloc(sizeof(float) * N_NODES);
    int*   partial = (int*)alloc(sizeof(int) * 256);
    float* bnacc = (float*)alloc(sizeof(float) * 2 * HID);
    if ((size_t)(p - (char*)d_ws) > ws_size) return;   // visible failure if ws too small

    u16*   hbuf = (u16*)reg1;
    const int RG = 3 * 2 * BATCH;   // 24576 rows per pool
    float* G_D  = (float*)reg1;
    float* G_T  = G_D + (size_t)RG * HID;
    float* H_D  = emb0;                            // overlays emb (dead after gather)
    float* H_T  = H_D + (size_t)RG * HID;
    float* P_D  = emb1;
    float* P_T  = P_D + (size_t)2 * BATCH * HID;
    float* e_D  = ebuf;
    float* e_T  = ebuf + RG;
    float* embp[3] = {emb0, emb1, emb2};

    // ---- CSR build ----
    hipMemsetAsync(cnt, 0, sizeof(int) * (size_t)2 * N_NODES, stream);
    count_deg<<<(N_EDGES + 255) / 256, 256, 0, stream>>>(dstp, cnt);
    scan_s1<<<SCAN_NB, 256, 0, stream>>>(cnt, rowstart, partial);
    scan_s2<<<1, 256, 0, stream>>>(partial, rowstart);
    scan_s3_dinv<<<SCAN_NB, 256, 0, stream>>>(rowstart, partial, cnt, dinvp);
    scatter_edges<<<(N_EDGES + 255) / 256, 256, 0, stream>>>(srcp, dstp, rowstart, cursor, csr);

    // ---- 3 GCN layers ----
    const int NB = (N_NODES + 127) / 128;
    for (int l = 0; l < 3; ++l) {
        int din = (l == 0) ? IN_DIM : HID;
        f32_split_bf16<<<(HID * din + 255) / 256, 256, 0, stream>>>(gcn_w[l], wh, wl, HID * din);
        const float* Ain = (l == 0) ? x : embp[l - 1];
        mfma_gemm<true><<<NB, 256, 0, stream>>>(Ain, wh, wl, hbuf, N_NODES, din);
        agg_relu<<<(N_NODES + 3) / 4, 256, 0, stream>>>(hbuf, dinvp, rowstart, csr, gcn_b[l], embp[l]);
        hipMemsetAsync(bnacc, 0, sizeof(float) * 2 * HID, stream);
        bn_reduce<<<200, 256, 0, stream>>>(embp[l], bnacc);
        bn_apply<<<((size_t)N_NODES * HID + 255) / 256, 256, 0, stream>>>(embp[l], bnacc, gamma, beta);
    }

    // ---- attention pooling (fp32) ----
    const int GU4 = RG * (HID / 4);
    gather_G<<<dim3((GU4 + 255) / 256, 2), 256, 0, stream>>>(
        emb0, emb1, emb2, drug_pos, drug_neg, target_pos, target_neg, G_D, G_T);

    f32_split_bf16_2<<<(2 * HID * HID + 255) / 256, 256, 0, stream>>>(W_D, W_T, whDT, wlDT, HID * HID);
    mfma_gemm<false><<<RG / 128, 256, 0, stream>>>(G_D, whDT, wlDT, H_D, RG, HID);
    mfma_gemm<false><<<RG / 128, 256, 0, stream>>>(G_T, whDT + HID * HID, wlDT + HID * HID, H_T, RG, HID);
    lrelu_dotq<<<dim3(RG / 4, 2), 256, 0, stream>>>(H_D, H_T, q_D, q_T, e_D, e_T, RG);
    softmax_pool<<<dim3(2 * BATCH, 2), HID, 0, stream>>>(G_D, G_T, e_D, e_T, P_D, P_T);

    // ---- output head ----
    transpose_k<<<(OUT_DIM * HID + 255) / 256, 256, 0, stream>>>(out_w, wt, OUT_DIM, HID);
    head_gemm<<<dim3(BATCH / 64, 4), 256, 0, stream>>>(P_D, P_T, wt, out_b, out);
}

// Round 7
// 588.390 us; speedup vs baseline: 1.7433x; 1.1018x over previous
//
#include <hip/hip_runtime.h>
#include <hip/hip_fp16.h>
#include <cstdint>

#define N_NODES 50000
#define IN_DIM  256
#define HID     128
#define OUT_DIM 64
#define N_EDGES 800000
#define BATCH   4096
#define BN_EPS  1e-5f
#define SLOPE   0.01f

typedef unsigned short u16;
typedef __attribute__((ext_vector_type(8))) short bf16x8;
typedef __attribute__((ext_vector_type(4))) float f32x4;

__device__ __forceinline__ u16 f2bf(float f) {
    union { float f; unsigned u; } v; v.f = f;
    unsigned r = v.u + 0x7FFF + ((v.u >> 16) & 1);   // RNE
    return (u16)(r >> 16);
}
__device__ __forceinline__ float bf2f(u16 b) {
    union { unsigned u; float f; } v; v.u = ((unsigned)b) << 16;
    return v.f;
}
__device__ __forceinline__ void splitbf(float v, u16* hi, u16* lo) {
    u16 h = f2bf(v);
    *hi = h;
    *lo = f2bf(v - bf2f(h));
}

// ---------------- prep: all weight splits + transpose + zero-init in ONE kernel ----------

#define PREP_S0 (HID * IN_DIM)                // gcn_w0 split
#define PREP_S1 (PREP_S0 + HID * HID)         // gcn_w1
#define PREP_S2 (PREP_S1 + HID * HID)         // gcn_w2
#define PREP_S3 (PREP_S2 + HID * HID)         // W_D
#define PREP_S4 (PREP_S3 + HID * HID)         // W_T
#define PREP_S5 (PREP_S4 + OUT_DIM * HID)     // out_w transpose
#define PREP_S6 (PREP_S5 + 3 * 2 * HID)       // bnacc3 zero (768)
#define PREP_TOT (PREP_S6 + 256)              // bucketCnt zero

__global__ void prep(const float* __restrict__ w0, const float* __restrict__ w1,
                     const float* __restrict__ w2, const float* __restrict__ WD,
                     const float* __restrict__ WT, const float* __restrict__ out_w,
                     u16* __restrict__ wh0, u16* __restrict__ wl0,
                     u16* __restrict__ wh1, u16* __restrict__ wl1,
                     u16* __restrict__ wh2, u16* __restrict__ wl2,
                     u16* __restrict__ whDT, u16* __restrict__ wlDT,
                     float* __restrict__ wt, float* __restrict__ bnacc3,
                     int* __restrict__ bucketCnt) {
    int i = blockIdx.x * 256 + threadIdx.x;
    if (i < PREP_S0) {
        splitbf(w0[i], &wh0[i], &wl0[i]);
    } else if (i < PREP_S1) {
        int j = i - PREP_S0; splitbf(w1[j], &wh1[j], &wl1[j]);
    } else if (i < PREP_S2) {
        int j = i - PREP_S1; splitbf(w2[j], &wh2[j], &wl2[j]);
    } else if (i < PREP_S3) {
        int j = i - PREP_S2; splitbf(WD[j], &whDT[j], &wlDT[j]);
    } else if (i < PREP_S4) {
        int j = i - PREP_S3; splitbf(WT[j], &whDT[HID * HID + j], &wlDT[HID * HID + j]);
    } else if (i < PREP_S5) {
        int j = i - PREP_S4;                  // wt[k][n] = out_w[n][k]
        int k = j >> 6, n = j & 63;
        wt[j] = out_w[n * HID + k];
    } else if (i < PREP_S6) {
        bnacc3[i - PREP_S5] = 0.f;
    } else if (i < PREP_TOT) {
        int j = i - PREP_S6;
        if (j < 256) bucketCnt[j] = 0;
    }
}

// ---------------- bucketed CSR build ----------------
// bucket b = dst >> 8; NBKT buckets of 256 nodes; csr region per bucket is contiguous.

#define NBKT 196                               // ceil(50000/256)
#define PASSA_CHUNK 2048
#define NB_A ((N_EDGES + PASSA_CHUNK - 1) / PASSA_CHUNK)   // 391

__global__ void bucket_count(const int* __restrict__ dst, int* __restrict__ bucketCnt) {
    __shared__ int hist[NBKT];
    int t = threadIdx.x;
    if (t < NBKT) hist[t] = 0;
    __syncthreads();
    int b0 = blockIdx.x * PASSA_CHUNK;
    int b1 = min(b0 + PASSA_CHUNK, N_EDGES);
    for (int i = b0 + t; i < b1; i += 256)
        atomicAdd(&hist[dst[i] >> 8], 1);
    __syncthreads();
    if (t < NBKT && hist[t] > 0) atomicAdd(&bucketCnt[t], hist[t]);
}

__global__ void bucket_scan(const int* __restrict__ bucketCnt, int* __restrict__ bucketBase,
                            int* __restrict__ gcursor, int* __restrict__ rowstart) {
    __shared__ int s[256];
    int t = threadIdx.x;
    int v = (t < NBKT) ? bucketCnt[t] : 0;
    s[t] = v;
    __syncthreads();
#pragma unroll
    for (int off = 1; off < 256; off <<= 1) {
        int tmp = (t >= off) ? s[t - off] : 0;
        __syncthreads();
        s[t] += tmp;
        __syncthreads();
    }
    if (t < NBKT) { bucketBase[t] = s[t] - v; gcursor[t] = s[t] - v; }
    if (t == 0) { bucketBase[NBKT] = N_EDGES; rowstart[N_NODES] = N_EDGES; }
}

// scatter packed (dstLow<<16 | src) into bucket-contiguous pair regions
__global__ void bucket_scatter(const int* __restrict__ src, const int* __restrict__ dst,
                               int* __restrict__ gcursor, unsigned* __restrict__ pairs) {
    __shared__ int hist[NBKT], base[NBKT], hist2[NBKT];
    int t = threadIdx.x;
    if (t < NBKT) { hist[t] = 0; hist2[t] = 0; }
    __syncthreads();
    int b0 = blockIdx.x * PASSA_CHUNK;
    int b1 = min(b0 + PASSA_CHUNK, N_EDGES);
    for (int i = b0 + t; i < b1; i += 256)
        atomicAdd(&hist[dst[i] >> 8], 1);
    __syncthreads();
    if (t < NBKT && hist[t] > 0) base[t] = atomicAdd(&gcursor[t], hist[t]);
    __syncthreads();
    for (int i = b0 + t; i < b1; i += 256) {
        int d = dst[i];
        int b = d >> 8;
        int lp = atomicAdd(&hist2[b], 1);
        pairs[base[b] + lp] = ((unsigned)(d & 255) << 16) | (unsigned)src[i];
    }
}

// per bucket: per-node counts -> rowstart + dinv, then scatter csr in private region
__global__ void bucket_build(const unsigned* __restrict__ pairs, const int* __restrict__ bucketBase,
                             int* __restrict__ rowstart, float* __restrict__ dinv,
                             int* __restrict__ csr) {
    __shared__ int cnt[256], s[256], lcur[256];
    int b = blockIdx.x, t = threadIdx.x;
    int pb0 = bucketBase[b], pb1 = bucketBase[b + 1];
    cnt[t] = 0;
    __syncthreads();
    for (int i = pb0 + t; i < pb1; i += 256)
        atomicAdd(&cnt[pairs[i] >> 16], 1);
    __syncthreads();
    int v = cnt[t];
    s[t] = v;
    __syncthreads();
#pragma unroll
    for (int off = 1; off < 256; off <<= 1) {
        int tmp = (t >= off) ? s[t - off] : 0;
        __syncthreads();
        s[t] += tmp;
        __syncthreads();
    }
    int node = (b << 8) + t;
    int start = pb0 + s[t] - v;
    if (node < N_NODES) {
        rowstart[node] = start;
        dinv[node] = rsqrtf(1.0f + (float)v);
    }
    lcur[t] = start;
    __syncthreads();
    for (int i = pb0 + t; i < pb1; i += 256) {
        unsigned pr = pairs[i];
        int pos = atomicAdd(&lcur[pr >> 16], 1);
        csr[pos] = (int)(pr & 0xFFFFu);
    }
}

// pack fp16(dinv[src]) into the high 16 bits of each csr entry (done once, used 3x)
__global__ void csr_pack(int* __restrict__ csr, const float* __restrict__ dinv) {
    int e = blockIdx.x * 256 + threadIdx.x;
    if (e < N_EDGES) {
        int sc = csr[e];
        __half hd = __float2half(dinv[sc]);
        csr[e] = ((int)*(u16*)&hd << 16) | sc;
    }
}

// ---------------- split-bf16 MFMA GEMM: C[M][128] = A[M][K](f32) @ W[128][K]^T --------------

template<bool OUT_F16>
__global__ __launch_bounds__(256) void mfma_gemm(const float* __restrict__ A,
                                                 const u16* __restrict__ Wh,
                                                 const u16* __restrict__ Wl,
                                                 void* __restrict__ Cout,
                                                 int M, int K) {
    __shared__ u16 Ah[128][40];
    __shared__ u16 Al[128][40];
    const int tid  = threadIdx.x;
    const int wave = tid >> 6, lane = tid & 63;
    const int lr   = lane & 15, quad = lane >> 4;
    const int rowBase = blockIdx.x * 128;

    f32x4 acc[2][8];
#pragma unroll
    for (int i = 0; i < 2; ++i)
#pragma unroll
        for (int j = 0; j < 8; ++j) acc[i][j] = (f32x4){0.f, 0.f, 0.f, 0.f};

    const int r = tid >> 1, hf = tid & 1;
    const int grow = rowBase + r;

    for (int kk = 0; kk < K; kk += 32) {
        u16 sh[16], sl[16];
        if (grow < M) {
            const float* src = A + (size_t)grow * K + kk + hf * 16;
#pragma unroll
            for (int i = 0; i < 4; ++i) {
                float4 v = ((const float4*)src)[i];
                float vv[4] = {v.x, v.y, v.z, v.w};
#pragma unroll
                for (int c = 0; c < 4; ++c) {
                    u16 h = f2bf(vv[c]);
                    sh[i * 4 + c] = h;
                    sl[i * 4 + c] = f2bf(vv[c] - bf2f(h));
                }
            }
        } else {
#pragma unroll
            for (int i = 0; i < 16; ++i) { sh[i] = 0; sl[i] = 0; }
        }
        *(uint4*)&Ah[r][hf * 16 + 0] = *(uint4*)&sh[0];
        *(uint4*)&Ah[r][hf * 16 + 8] = *(uint4*)&sh[8];
        *(uint4*)&Al[r][hf * 16 + 0] = *(uint4*)&sl[0];
        *(uint4*)&Al[r][hf * 16 + 8] = *(uint4*)&sl[8];
        __syncthreads();

        bf16x8 ah0 = *(const bf16x8*)&Ah[wave * 32 +      lr][quad * 8];
        bf16x8 ah1 = *(const bf16x8*)&Ah[wave * 32 + 16 + lr][quad * 8];
        bf16x8 al0 = *(const bf16x8*)&Al[wave * 32 +      lr][quad * 8];
        bf16x8 al1 = *(const bf16x8*)&Al[wave * 32 + 16 + lr][quad * 8];
#pragma unroll
        for (int ct = 0; ct < 8; ++ct) {
            size_t boff = (size_t)(ct * 16 + lr) * K + kk + quad * 8;
            bf16x8 bh = *(const bf16x8*)(Wh + boff);
            bf16x8 bl = *(const bf16x8*)(Wl + boff);
            acc[0][ct] = __builtin_amdgcn_mfma_f32_16x16x32_bf16(al0, bh, acc[0][ct], 0, 0, 0);
            acc[0][ct] = __builtin_amdgcn_mfma_f32_16x16x32_bf16(ah0, bl, acc[0][ct], 0, 0, 0);
            acc[0][ct] = __builtin_amdgcn_mfma_f32_16x16x32_bf16(ah0, bh, acc[0][ct], 0, 0, 0);
            acc[1][ct] = __builtin_amdgcn_mfma_f32_16x16x32_bf16(al1, bh, acc[1][ct], 0, 0, 0);
            acc[1][ct] = __builtin_amdgcn_mfma_f32_16x16x32_bf16(ah1, bl, acc[1][ct], 0, 0, 0);
            acc[1][ct] = __builtin_amdgcn_mfma_f32_16x16x32_bf16(ah1, bh, acc[1][ct], 0, 0, 0);
        }
        __syncthreads();
    }

#pragma unroll
    for (int rt = 0; rt < 2; ++rt) {
        int row0 = rowBase + wave * 32 + rt * 16 + quad * 4;
#pragma unroll
        for (int reg = 0; reg < 4; ++reg) {
            int row = row0 + reg;
            if (row < M) {
#pragma unroll
                for (int ct = 0; ct < 8; ++ct) {
                    if constexpr (OUT_F16) {
                        __half hv = __float2half(acc[rt][ct][reg]);
                        ((u16*)Cout)[(size_t)row * 128 + ct * 16 + lr] = *(u16*)&hv;
                    } else {
                        ((float*)Cout)[(size_t)row * 128 + ct * 16 + lr] = acc[rt][ct][reg];
                    }
                }
            }
        }
    }
}

// ---------------- GCN aggregation (fp16 gather, packed dinv) + bias + relu ----------------
// 1 node per wave, 4 waves/block; lane = 32*ep + q; edge loop unrolled x2 per lane-half.

__global__ __launch_bounds__(256) void agg_relu(const u16* __restrict__ h,
                                                const float* __restrict__ dinv,
                                                const int* __restrict__ rowstart,
                                                const int* __restrict__ csr,
                                                const float* __restrict__ bias,
                                                float* __restrict__ out) {
    int wave = threadIdx.x >> 6;
    int lane = threadIdx.x & 63;
    int n = blockIdx.x * 4 + wave;
    if (n >= N_NODES) return;
    int ep = lane >> 5;
    int q  = lane & 31;
    int s = rowstart[n], e1 = rowstart[n + 1];
    float ax = 0.f, ay = 0.f, az = 0.f, aw = 0.f;
    int e = s + ep;
    for (; e + 2 < e1; e += 4) {
        unsigned c0 = (unsigned)csr[e];
        unsigned c1 = (unsigned)csr[e + 2];
        u16 hd0 = (u16)(c0 >> 16), hd1 = (u16)(c1 >> 16);
        float dv0 = __half2float(*(const __half*)&hd0);
        float dv1 = __half2float(*(const __half*)&hd1);
        uint2 w0 = ((const uint2*)(h + (size_t)(c0 & 0xFFFFu) * HID))[q];
        uint2 w1 = ((const uint2*)(h + (size_t)(c1 & 0xFFFFu) * HID))[q];
        float2 a0 = __half22float2(*(const __half2*)&w0.x);
        float2 b0 = __half22float2(*(const __half2*)&w0.y);
        float2 a1 = __half22float2(*(const __half2*)&w1.x);
        float2 b1 = __half22float2(*(const __half2*)&w1.y);
        ax = fmaf(dv0, a0.x, ax); ay = fmaf(dv0, a0.y, ay);
        az = fmaf(dv0, b0.x, az); aw = fmaf(dv0, b0.y, aw);
        ax = fmaf(dv1, a1.x, ax); ay = fmaf(dv1, a1.y, ay);
        az = fmaf(dv1, b1.x, az); aw = fmaf(dv1, b1.y, aw);
    }
    if (e < e1) {
        unsigned c0 = (unsigned)csr[e];
        u16 hd0 = (u16)(c0 >> 16);
        float dv = __half2float(*(const __half*)&hd0);
        uint2 w0 = ((const uint2*)(h + (size_t)(c0 & 0xFFFFu) * HID))[q];
        float2 a0 = __half22float2(*(const __half2*)&w0.x);
        float2 b0 = __half22float2(*(const __half2*)&w0.y);
        ax = fmaf(dv, a0.x, ax); ay = fmaf(dv, a0.y, ay);
        az = fmaf(dv, b0.x, az); aw = fmaf(dv, b0.y, aw);
    }
    ax += __shfl_xor(ax, 32);
    ay += __shfl_xor(ay, 32);
    az += __shfl_xor(az, 32);
    aw += __shfl_xor(aw, 32);
    if (ep == 0) {
        float dn = dinv[n];
        float dn2 = dn * dn;
        uint2 hw = ((const uint2*)(h + (size_t)n * HID))[q];
        float2 h0 = __half22float2(*(const __half2*)&hw.x);
        float2 h1 = __half22float2(*(const __half2*)&hw.y);
        float4 bv = ((const float4*)bias)[q];
        float4 o;
        o.x = fmaxf(fmaf(ax, dn, fmaf(h0.x, dn2, bv.x)), 0.f);
        o.y = fmaxf(fmaf(ay, dn, fmaf(h0.y, dn2, bv.y)), 0.f);
        o.z = fmaxf(fmaf(az, dn, fmaf(h1.x, dn2, bv.z)), 0.f);
        o.w = fmaxf(fmaf(aw, dn, fmaf(h1.y, dn2, bv.w)), 0.f);
        ((float4*)(out + (size_t)n * HID))[q] = o;
    }
}

// ---------------- BatchNorm ----------------

__global__ void bn_reduce(const float* __restrict__ x, float* __restrict__ acc) {
    int f  = threadIdx.x & 127;
    int rs = threadIdx.x >> 7;
    const int RPB = (N_NODES + gridDim.x - 1) / gridDim.x;
    int r0 = blockIdx.x * RPB;
    int r1 = min(r0 + RPB, N_NODES);
    float s = 0.f, sq = 0.f;
    for (int r = r0 + rs; r < r1; r += 2) {
        float v = x[(size_t)r * HID + f];
        s += v;
        sq = fmaf(v, v, sq);
    }
    atomicAdd(&acc[f], s);
    atomicAdd(&acc[HID + f], sq);
}

__global__ void bn_apply(float* __restrict__ x, const float* __restrict__ acc,
                         const float* __restrict__ gamma, const float* __restrict__ beta) {
    size_t idx = (size_t)blockIdx.x * blockDim.x + threadIdx.x;
    if (idx < (size_t)N_NODES * HID) {
        int f = (int)(idx & 127);
        float mean = acc[f] * (1.0f / N_NODES);
        float var  = fmaxf(acc[HID + f] * (1.0f / N_NODES) - mean * mean, 0.f);
        float sc   = gamma[f] * rsqrtf(var + BN_EPS);
        x[idx] = (x[idx] - mean) * sc + beta[f];
    }
}

// ---------------- attention head (fp32), D/T batched via blockIdx.y ----------------

__global__ void gather_G(const float* __restrict__ e0, const float* __restrict__ e1,
                         const float* __restrict__ e2,
                         const int* __restrict__ dpos, const int* __restrict__ dneg,
                         const int* __restrict__ tpos, const int* __restrict__ tneg,
                         float* __restrict__ G_D, float* __restrict__ G_T) {
    int idx = blockIdx.x * blockDim.x + threadIdx.x;
    const int TOT = 3 * 2 * BATCH * (HID / 4);
    if (idx >= TOT) return;
    int q   = idx & 31;
    int row = idx >> 5;
    int l   = row / (2 * BATCH);
    int j   = row % (2 * BATCH);
    const int* ia = blockIdx.y ? tpos : dpos;
    const int* ib = blockIdx.y ? tneg : dneg;
    float* G = blockIdx.y ? G_T : G_D;
    int node = (j < BATCH) ? ia[j] : ib[j - BATCH];
    const float* e = (l == 0) ? e0 : (l == 1) ? e1 : e2;
    ((float4*)G)[idx] = ((const float4*)(e + (size_t)node * HID))[q];
}

__global__ void lrelu_dotq(const float* __restrict__ H_D, const float* __restrict__ H_T,
                           const float* __restrict__ q_D, const float* __restrict__ q_T,
                           float* __restrict__ e_D, float* __restrict__ e_T, int R) {
    int lane = threadIdx.x & 63;
    int wave = threadIdx.x >> 6;
    int r = blockIdx.x * 4 + wave;
    if (r >= R) return;
    const float* H = blockIdx.y ? H_T : H_D;
    const float* q = blockIdx.y ? q_T : q_D;
    float* e = blockIdx.y ? e_T : e_D;
    float a = 0.f;
#pragma unroll
    for (int t = 0; t < 2; ++t) {
        int k = lane + 64 * t;
        float v = H[(size_t)r * HID + k];
        v = (v > 0.f) ? v : SLOPE * v;
        a = fmaf(v, q[k], a);
    }
    for (int off = 32; off > 0; off >>= 1) a += __shfl_down(a, off, 64);
    if (lane == 0) e[r] = a;
}

__global__ void softmax_pool(const float* __restrict__ G_D, const float* __restrict__ G_T,
                             const float* __restrict__ e_D, const float* __restrict__ e_T,
                             float* __restrict__ P_D, float* __restrict__ P_T) {
    int j = blockIdx.x;
    int f = threadIdx.x;
    const float* G = blockIdx.y ? G_T : G_D;
    const float* e = blockIdx.y ? e_T : e_D;
    float* P = blockIdx.y ? P_T : P_D;
    float e0 = e[j], e1 = e[2 * BATCH + j], e2 = e[4 * BATCH + j];
    float m = fmaxf(e0, fmaxf(e1, e2));
    float a0 = expf(e0 - m), a1 = expf(e1 - m), a2 = expf(e2 - m);
    float inv = 1.0f / (a0 + a1 + a2);
    float p = a0 * G[((size_t)0 * 2 * BATCH + j) * HID + f]
            + a1 * G[((size_t)1 * 2 * BATCH + j) * HID + f]
            + a2 * G[((size_t)2 * 2 * BATCH + j) * HID + f];
    P[(size_t)j * HID + f] = p * inv;
}

// ---------------- output head: 4 segments batched via blockIdx.y ----------------

__global__ __launch_bounds__(256) void head_gemm(const float* __restrict__ P_D,
                                                 const float* __restrict__ P_T,
                                                 const float* __restrict__ B,
                                                 const float* __restrict__ bias,
                                                 float* __restrict__ out) {
    constexpr int BM = 64, BK = 32, BN = OUT_DIM, TM = 4, TN = 4;
    __shared__ float As[BK][BM];
    __shared__ float Bs[BK][BN];
    const int y = blockIdx.y;
    const float* A = ((y & 1) ? P_T : P_D) + (size_t)(y >> 1) * BATCH * HID;
    float* C = out + (size_t)y * BATCH * OUT_DIM;
    const int tid = threadIdx.x;
    const int tx = tid & 15, ty = tid >> 4;
    const int rowBase = blockIdx.x * BM;
    float acc[TM][TN];
#pragma unroll
    for (int i = 0; i < TM; ++i)
#pragma unroll
        for (int j = 0; j < TN; ++j) acc[i][j] = 0.f;

    for (int kk = 0; kk < HID; kk += BK) {
#pragma unroll
        for (int i = tid; i < (BM * BK) / 4; i += 256) {
            int m  = i >> 3;
            int kq = i & 7;
            float4 v = *(const float4*)(A + (size_t)(rowBase + m) * HID + kk + kq * 4);
            As[kq * 4 + 0][m] = v.x;
            As[kq * 4 + 1][m] = v.y;
            As[kq * 4 + 2][m] = v.z;
            As[kq * 4 + 3][m] = v.w;
        }
#pragma unroll
        for (int i = tid; i < (BK * BN) / 4; i += 256) {
            int k  = i / (BN / 4);
            int n4 = i % (BN / 4);
            *(float4*)&Bs[k][n4 * 4] = *(const float4*)(B + (size_t)(kk + k) * BN + n4 * 4);
        }
        __syncthreads();
#pragma unroll 8
        for (int k = 0; k < BK; ++k) {
            float a[TM], b[TN];
#pragma unroll
            for (int i = 0; i < TM; ++i) a[i] = As[k][ty * TM + i];
#pragma unroll
            for (int j = 0; j < TN; ++j) b[j] = Bs[k][tx * TN + j];
#pragma unroll
            for (int i = 0; i < TM; ++i)
#pragma unroll
                for (int j = 0; j < TN; ++j)
                    acc[i][j] = fmaf(a[i], b[j], acc[i][j]);
        }
        __syncthreads();
    }
#pragma unroll
    for (int i = 0; i < TM; ++i) {
        int grow = rowBase + ty * TM + i;
#pragma unroll
        for (int j = 0; j < TN; ++j)
            C[(size_t)grow * BN + tx * TN + j] = acc[i][j] + bias[tx * TN + j];
    }
}

// ---------------- host ----------------

extern "C" void kernel_launch(void* const* d_in, const int* in_sizes, int n_in,
                              void* d_out, int out_size, void* d_ws, size_t ws_size,
                              hipStream_t stream) {
    const float* x          = (const float*)d_in[0];
    const int*   ei         = (const int*)d_in[1];
    const int*   srcp       = ei;
    const int*   dstp       = ei + N_EDGES;
    const int*   drug_pos   = (const int*)d_in[2];
    const int*   target_pos = (const int*)d_in[3];
    const int*   drug_neg   = (const int*)d_in[4];
    const int*   target_neg = (const int*)d_in[5];
    const float* gcn_w[3]   = {(const float*)d_in[7], (const float*)d_in[9], (const float*)d_in[11]};
    const float* gcn_b[3]   = {(const float*)d_in[8], (const float*)d_in[10], (const float*)d_in[12]};
    const float* gamma      = (const float*)d_in[13];
    const float* beta       = (const float*)d_in[14];
    const float* W_D        = (const float*)d_in[15];
    const float* W_T        = (const float*)d_in[16];
    const float* q_D        = (const float*)d_in[17];
    const float* q_T        = (const float*)d_in[18];
    const float* out_w      = (const float*)d_in[19];
    const float* out_b      = (const float*)d_in[20];
    float*       out        = (float*)d_out;

    // ---- workspace (~110 MB) with phase overlays ----
    char* p = (char*)d_ws;
    auto alloc = [&](size_t bytes) -> char* {
        char* r = p;
        p += (bytes + 255) & ~(size_t)255;
        return r;
    };
    // region1 (25.6 MB): layers = h (fp16); pools = G_D+G_T (fp32)
    char*  reg1  = alloc(sizeof(float) * (size_t)N_NODES * HID);
    // region2 (76.8 MB): layers = emb0..2; pools overlay H/P
    float* emb0  = (float*)alloc(sizeof(float) * (size_t)N_NODES * HID);
    float* emb1  = (float*)alloc(sizeof(float) * (size_t)N_NODES * HID);
    float* emb2  = (float*)alloc(sizeof(float) * (size_t)N_NODES * HID);
    // small persistent
    float* ebuf  = (float*)alloc(sizeof(float) * (size_t)2 * 3 * 2 * BATCH);
    u16*   wh0   = (u16*)alloc(sizeof(u16) * HID * IN_DIM);
    u16*   wl0   = (u16*)alloc(sizeof(u16) * HID * IN_DIM);
    u16*   wh1   = (u16*)alloc(sizeof(u16) * HID * HID);
    u16*   wl1   = (u16*)alloc(sizeof(u16) * HID * HID);
    u16*   wh2   = (u16*)alloc(sizeof(u16) * HID * HID);
    u16*   wl2   = (u16*)alloc(sizeof(u16) * HID * HID);
    u16*   whDT  = (u16*)alloc(sizeof(u16) * 2 * HID * HID);
    u16*   wlDT  = (u16*)alloc(sizeof(u16) * 2 * HID * HID);
    float* wt    = (float*)alloc(sizeof(float) * OUT_DIM * HID);
    int*   rowstart = (int*)alloc(sizeof(int) * (N_NODES + 1));
    int*   csr   = (int*)alloc(sizeof(int) * N_EDGES);
    unsigned* pairs = (unsigned*)alloc(sizeof(unsigned) * N_EDGES);
    float* dinvp = (float*)alloc(sizeof(float) * N_NODES);
    int*   bucketCnt  = (int*)alloc(sizeof(int) * 256);
    int*   bucketBase = (int*)alloc(sizeof(int) * (NBKT + 1));
    int*   gcursor    = (int*)alloc(sizeof(int) * 256);
    float* bnacc3 = (float*)alloc(sizeof(float) * 3 * 2 * HID);
    if ((size_t)(p - (char*)d_ws) > ws_size) return;   // visible failure if ws too small

    u16*   hbuf = (u16*)reg1;
    const int RG = 3 * 2 * BATCH;
    float* G_D  = (float*)reg1;
    float* G_T  = G_D + (size_t)RG * HID;
    float* H_D  = emb0;
    float* H_T  = H_D + (size_t)RG * HID;
    float* P_D  = emb1;
    float* P_T  = P_D + (size_t)2 * BATCH * HID;
    float* e_D  = ebuf;
    float* e_T  = ebuf + RG;
    float* embp[3] = {emb0, emb1, emb2};
    const u16* whp[3] = {wh0, wh1, wh2};
    const u16* wlp[3] = {wl0, wl1, wl2};

    // ---- prep (weights + zero-init, one kernel) ----
    prep<<<(PREP_TOT + 255) / 256, 256, 0, stream>>>(
        gcn_w[0], gcn_w[1], gcn_w[2], W_D, W_T, out_w,
        wh0, wl0, wh1, wl1, wh2, wl2, whDT, wlDT, wt, bnacc3, bucketCnt);

    // ---- bucketed CSR build ----
    bucket_count<<<NB_A, 256, 0, stream>>>(dstp, bucketCnt);
    bucket_scan<<<1, 256, 0, stream>>>(bucketCnt, bucketBase, gcursor, rowstart);
    bucket_scatter<<<NB_A, 256, 0, stream>>>(srcp, dstp, gcursor, pairs);
    bucket_build<<<NBKT, 256, 0, stream>>>(pairs, bucketBase, rowstart, dinvp, csr);
    csr_pack<<<(N_EDGES + 255) / 256, 256, 0, stream>>>(csr, dinvp);

    // ---- 3 GCN layers ----
    const int NB = (N_NODES + 127) / 128;
    for (int l = 0; l < 3; ++l) {
        int din = (l == 0) ? IN_DIM : HID;
        const float* Ain = (l == 0) ? x : embp[l - 1];
        mfma_gemm<true><<<NB, 256, 0, stream>>>(Ain, whp[l], wlp[l], hbuf, N_NODES, din);
        agg_relu<<<(N_NODES + 3) / 4, 256, 0, stream>>>(hbuf, dinvp, rowstart, csr, gcn_b[l], embp[l]);
        bn_reduce<<<200, 256, 0, stream>>>(embp[l], bnacc3 + l * 2 * HID);
        bn_apply<<<((size_t)N_NODES * HID + 255) / 256, 256, 0, stream>>>(
            embp[l], bnacc3 + l * 2 * HID, gamma, beta);
    }

    // ---- attention pooling (fp32) ----
    const int GU4 = RG * (HID / 4);
    gather_G<<<dim3((GU4 + 255) / 256, 2), 256, 0, stream>>>(
        emb0, emb1, emb2, drug_pos, drug_neg, target_pos, target_neg, G_D, G_T);

    mfma_gemm<false><<<RG / 128, 256, 0, stream>>>(G_D, whDT, wlDT, H_D, RG, HID);
    mfma_gemm<false><<<RG / 128, 256, 0, stream>>>(G_T, whDT + HID * HID, wlDT + HID * HID, H_T, RG, HID);
    lrelu_dotq<<<dim3(RG / 4, 2), 256, 0, stream>>>(H_D, H_T, q_D, q_T, e_D, e_T, RG);
    softmax_pool<<<dim3(2 * BATCH, 2), HID, 0, stream>>>(G_D, G_T, e_D, e_T, P_D, P_T);

    // ---- output head ----
    head_gemm<<<dim3(BATCH / 64, 4), 256, 0, stream>>>(P_D, P_T, wt, out_b, out);
}